// Round 13
// baseline (2084.662 us; speedup 1.0000x reference)
//
#include <hip/hip_runtime.h>
#include <hip/hip_bf16.h>

using bf16 = __hip_bfloat16;
using short8  = __attribute__((ext_vector_type(8))) short;
using floatx4 = __attribute__((ext_vector_type(4))) float;
using ull = unsigned long long;

constexpr int Bn = 4, Np = 1024, Gn = 128, Kn = 32;
constexpr int DM = 384, DEPTH = 12, CLSn = 40;
constexpr int DI = 768, DSt = 16, DTR = 24;
constexpr int Ln = 384;
constexpr int NCH = 12, CHS = 32;      // scan: 12 chunks x 32 steps
constexpr int NLC = 24;                // conv: 24 chunks x 16 steps
constexpr float EPSf = 1e-5f;
constexpr float BNS = 0.99999500003749968752f; // 1/sqrt(1+1e-5)
constexpr float LOG2E = 1.4426950408889634f;

static __device__ __forceinline__ short f2bf(float f){
  bf16 h = __float2bfloat16(f);
  return *reinterpret_cast<short*>(&h);
}
static __device__ __forceinline__ float fsig(float x){ return 1.f/(1.f + __expf(-x)); }
static __device__ __forceinline__ float fsoftplus(float x){
  return fmaxf(x, 0.f) + __logf(1.f + __expf(-fabsf(x)));
}

template<int CTRL>
static __device__ __forceinline__ int dppmov(int x){
  return __builtin_amdgcn_update_dpp(0, x, CTRL, 0xF, 0xF, true);
}
static __device__ __forceinline__ ull redmax64(ull key){
  #define RSTEP(CTRL) { \
    int hi = (int)(unsigned)(key >> 32), lo = (int)(unsigned)key; \
    int h2 = dppmov<CTRL>(hi), l2 = dppmov<CTRL>(lo); \
    ull k2 = ((ull)(unsigned)h2 << 32) | (unsigned)l2; \
    if (k2 > key) key = k2; }
  RSTEP(0x111) RSTEP(0x112) RSTEP(0x114) RSTEP(0x118) RSTEP(0x142) RSTEP(0x143)
  #undef RSTEP
  return key;
}

// ---------------------------------------------------------------- FPS (+fused 3-axis argsort)
__global__ __launch_bounds__(64) void fps_kernel(const float* __restrict__ pts,
                                                 float* __restrict__ center,
                                                 int* __restrict__ order){
  int b = blockIdx.x, t = threadIdx.x;
  __shared__ float xs[1024], ys[1024], zs[1024];
  __shared__ float cenx[Gn], ceny[Gn], cenz[Gn];
  const float* p = pts + (size_t)b * Np * 3;
  float X[16], Y[16], Z[16], D[16];
  #pragma unroll
  for (int i = 0; i < 16; ++i){
    int n = t + 64*i;
    float a = p[n*3+0], c = p[n*3+1], e = p[n*3+2];
    X[i] = a; Y[i] = c; Z[i] = e;
    xs[n] = a; ys[n] = c; zs[n] = e;
    D[i] = 1e10f;
  }
  __syncthreads();
  float px = xs[0], py = ys[0], pz = zs[0];
  if (t == 0){
    center[(size_t)(b*Gn)*3+0] = px;
    center[(size_t)(b*Gn)*3+1] = py;
    center[(size_t)(b*Gn)*3+2] = pz;
    cenx[0] = px; ceny[0] = py; cenz[0] = pz;
  }
  for (int it = 1; it < Gn; ++it){
    float v = -1.f; int nbest = t;
    #pragma unroll
    for (int i = 0; i < 16; ++i){
      float dx = __fsub_rn(X[i], px);
      float dy = __fsub_rn(Y[i], py);
      float dz = __fsub_rn(Z[i], pz);
      float d  = __fadd_rn(__fadd_rn(__fmul_rn(dx,dx), __fmul_rn(dy,dy)), __fmul_rn(dz,dz));
      float dm = fminf(D[i], d); D[i] = dm;
      if (dm > v){ v = dm; nbest = t + 64*i; }
    }
    ull key = ((ull)__float_as_uint(v) << 32) | (unsigned)(Np-1 - nbest);
    key = redmax64(key);
    int lo63 = __builtin_amdgcn_readlane((int)(unsigned)(key & 0xFFFFFFFFu), 63);
    int wn = Np-1 - lo63;
    wn = min(max(wn, 0), Np-1);
    px = xs[wn]; py = ys[wn]; pz = zs[wn];
    if (t == 0){
      center[(size_t)(b*Gn+it)*3+0] = px;
      center[(size_t)(b*Gn+it)*3+1] = py;
      center[(size_t)(b*Gn+it)*3+2] = pz;
      cenx[it] = px; ceny[it] = py; cenz[it] = pz;
    }
  }
  __syncthreads();
  // fused stable argsort (rank count), identical semantics to old sort_kernel
  for (int g = t; g < Gn; g += 64){
    #pragma unroll
    for (int ax = 0; ax < 3; ++ax){
      const float* key = (ax==0) ? cenx : (ax==1) ? ceny : cenz;
      float kt = key[g]; int r = 0;
      for (int j = 0; j < Gn; ++j){
        float kj = key[j];
        r += (kj < kt || (kj == kt && j < g)) ? 1 : 0;
      }
      r = min(max(r, 0), Gn-1);
      order[b*Ln + ax*Gn + r] = g;
    }
  }
}

// ---------------------------------------------------------------- KNN
__global__ __launch_bounds__(256) void knn_kernel(const float* __restrict__ pts,
                                                  const float* __restrict__ center,
                                                  float* __restrict__ nb){
  int gid = blockIdx.x; int b = gid >> 7;
  __shared__ float d2[1024];
  __shared__ float rv[4]; __shared__ int ri[4];
  int t = threadIdx.x;
  float cx = center[(size_t)gid*3+0], cy = center[(size_t)gid*3+1], cz = center[(size_t)gid*3+2];
  const float* p = pts + (size_t)b * Np * 3;
  for (int n = t; n < Np; n += 256){
    float dx = __fsub_rn(cx, p[n*3+0]);
    float dy = __fsub_rn(cy, p[n*3+1]);
    float dz = __fsub_rn(cz, p[n*3+2]);
    d2[n] = __fadd_rn(__fadd_rn(__fmul_rn(dx,dx), __fmul_rn(dy,dy)), __fmul_rn(dz,dz));
  }
  __syncthreads();
  for (int kk = 0; kk < Kn; ++kk){
    float v = 3e38f; int idx = 0;
    for (int n = t; n < Np; n += 256){
      float d = d2[n];
      if (d < v || (d == v && n < idx)){ v = d; idx = n; }
    }
    ull key = ((ull)(unsigned)(~__float_as_uint(v)) << 32) | (unsigned)(Np-1 - idx);
    key = redmax64(key);
    if ((t & 63) == 63){
      rv[t>>6] = __uint_as_float(~(unsigned)(key >> 32));
      ri[t>>6] = Np-1 - (int)(unsigned)(key & 0xFFFFFFFFu);
    }
    __syncthreads();
    if (t == 0){
      float bv = rv[0]; int bi = ri[0];
      for (int w = 1; w < 4; ++w){
        if (rv[w] < bv || (rv[w] == bv && ri[w] < bi)){ bv = rv[w]; bi = ri[w]; }
      }
      bi = min(max(bi, 0), Np-1);
      nb[((size_t)gid*Kn+kk)*3+0] = __fsub_rn(p[bi*3+0], cx);
      nb[((size_t)gid*Kn+kk)*3+1] = __fsub_rn(p[bi*3+1], cy);
      nb[((size_t)gid*Kn+kk)*3+2] = __fsub_rn(p[bi*3+2], cz);
      d2[bi] = 3e38f;
    }
    __syncthreads();
  }
}

// ---------------------------------------------------------------- all weight conversions, one dispatch
// dst segments are contiguous in WB: [ip | op | xp | e2 | e3 | e4]
__global__ __launch_bounds__(256) void cvt_all(const float* __restrict__ s0,
    const float* __restrict__ s1, const float* __restrict__ s2,
    const float* __restrict__ s3, const float* __restrict__ s4,
    const float* __restrict__ s5, bf16* __restrict__ dst){
  long i = ((long)blockIdx.x*256 + threadIdx.x)*4;
  if (i >= 11624448L) return;
  const float* s; long off;
  if      (i <  7077888L){ s = s0; off = 0L; }
  else if (i < 10616832L){ s = s1; off =  7077888L; }
  else if (i < 11132928L){ s = s2; off = 10616832L; }
  else if (i < 11165696L){ s = s3; off = 11132928L; }
  else if (i < 11427840L){ s = s4; off = 11165696L; }
  else                   { s = s5; off = 11427840L; }
  float4 v = *(const float4*)(s + (i - off));
  short* o = (short*)dst + i;
  o[0] = f2bf(v.x); o[1] = f2bf(v.y); o[2] = f2bf(v.z); o[3] = f2bf(v.w);
}

__global__ __launch_bounds__(256) void zero_flags(int* __restrict__ f){
  if (threadIdx.x < 160) f[threadIdx.x] = 0;
}

// ---------------------------------------------------------------- MFMA GEMM 64x64
// MODE 0: plain A. MODE 1 (GATE): A=y(lda), z at gz + m*1536 + 768 + k; el = y*silu(z).
template<typename AT, typename WT, int ACT, int MODE>
__global__ __launch_bounds__(256) void gemm_mfma(const AT* __restrict__ A, int lda,
                                                 const WT* __restrict__ W,
                                                 const float* __restrict__ bias,
                                                 const float* __restrict__ gz,
                                                 const float* __restrict__ bbp,
                                                 float* __restrict__ C, int ldc,
                                                 int M, int N, int K){
  __shared__ __align__(16) short As[64*40];
  __shared__ __align__(16) short Ws[64*40];
  int bm = blockIdx.x * 64, bn = blockIdx.y * 64;
  int t = threadIdx.x;
  int row = t >> 2;
  int kseg = (t & 3) * 8;
  int w = t >> 6, lane = t & 63, m16 = lane & 15, q = lane >> 4;
  bool kvec = ((K & 3) == 0) && ((lda & 3) == 0 || sizeof(AT) == 2);
  floatx4 acc[4] = {};
  for (int k0 = 0; k0 < K; k0 += 32){
    if constexpr (MODE == 1){
      const float* Yr = (const float*)A + (size_t)(bm + row)*lda + k0 + kseg;
      const float* Zr = gz + (size_t)(bm + row)*1536 + 768 + k0 + kseg;
      float y[8], z[8];
      *(float4*)&y[0] = *(const float4*)Yr;  *(float4*)&y[4] = *(const float4*)(Yr + 4);
      *(float4*)&z[0] = *(const float4*)Zr;  *(float4*)&z[4] = *(const float4*)(Zr + 4);
      short* dst = &As[row*40 + kseg];
      #pragma unroll
      for (int jj = 0; jj < 8; ++jj) dst[jj] = f2bf(y[jj] * (z[jj] * fsig(z[jj])));
    } else if constexpr (sizeof(AT) == 2){
      *(short8*)&As[row*40 + kseg] =
          *(const short8*)((const short*)A + (size_t)(bm + row)*lda + k0 + kseg);
    } else {
      const float* Ar = (const float*)A + (size_t)(bm + row)*lda;
      short* dst = &As[row*40 + kseg];
      if (kvec && (k0 + kseg + 8 <= K)){
        float4 a0 = *(const float4*)(Ar + k0 + kseg);
        float4 a1 = *(const float4*)(Ar + k0 + kseg + 4);
        dst[0]=f2bf(a0.x); dst[1]=f2bf(a0.y); dst[2]=f2bf(a0.z); dst[3]=f2bf(a0.w);
        dst[4]=f2bf(a1.x); dst[5]=f2bf(a1.y); dst[6]=f2bf(a1.z); dst[7]=f2bf(a1.w);
      } else {
        #pragma unroll
        for (int j = 0; j < 8; ++j){
          int k = k0 + kseg + j;
          dst[j] = (k < K) ? f2bf(Ar[k]) : (short)0;
        }
      }
    }
    if constexpr (sizeof(WT) == 2){
      int n = bn + row;
      short8 v;
      #pragma unroll
      for (int j = 0; j < 8; ++j) v[j] = 0;
      if (n < N) v = *(const short8*)((const short*)W + (size_t)n*K + k0 + kseg);
      *(short8*)&Ws[row*40 + kseg] = v;
    } else {
      int n = bn + row;
      short* dst = &Ws[row*40 + kseg];
      if (n < N && ((K & 3) == 0) && (k0 + kseg + 8 <= K)){
        const float* Wr = (const float*)W + (size_t)n*K + k0 + kseg;
        float4 w0 = *(const float4*)Wr;
        float4 w1 = *(const float4*)(Wr + 4);
        dst[0]=f2bf(w0.x); dst[1]=f2bf(w0.y); dst[2]=f2bf(w0.z); dst[3]=f2bf(w0.w);
        dst[4]=f2bf(w1.x); dst[5]=f2bf(w1.y); dst[6]=f2bf(w1.z); dst[7]=f2bf(w1.w);
      } else {
        #pragma unroll
        for (int j = 0; j < 8; ++j){
          int k = k0 + kseg + j;
          dst[j] = (n < N && k < K) ? f2bf(((const float*)W)[(size_t)n*K + k]) : (short)0;
        }
      }
    }
    __syncthreads();
    short8 af = *(const short8*)&As[(w*16 + m16)*40 + q*8];
    #pragma unroll
    for (int j = 0; j < 4; ++j){
      short8 bfr = *(const short8*)&Ws[(j*16 + m16)*40 + q*8];
      acc[j] = __builtin_amdgcn_mfma_f32_16x16x32_bf16(af, bfr, acc[j], 0, 0, 0);
    }
    __syncthreads();
  }
  #pragma unroll
  for (int j = 0; j < 4; ++j){
    int n = bn + j*16 + m16;
    if (n < N){
      float bv = bias ? bias[n] : 0.f;
      float gv = 0.f, bbv = 0.f;
      if (ACT == 1){ gv = gz[n] * BNS; bbv = bbp[n]; }
      #pragma unroll
      for (int r = 0; r < 4; ++r){
        int m = bm + w*16 + q*4 + r;
        float v = acc[j][r] + bv;
        if (ACT == 1){ v = v * gv + bbv; v = fmaxf(v, 0.f); }
        C[(size_t)m*ldc + n] = v;
      }
    }
  }
}

// ---------------------------------------------------------------- MFMA GEMM 128x128
template<typename AT, typename WT, int ACT>
__global__ __launch_bounds__(256) void gemm_mfma_128(const AT* __restrict__ A, int lda,
                                                     const WT* __restrict__ W,
                                                     const float* __restrict__ bias,
                                                     const float* __restrict__ g,
                                                     const float* __restrict__ bb,
                                                     float* __restrict__ C, int ldc,
                                                     int M, int N, int K){
  __shared__ __align__(16) short As[128*40];
  __shared__ __align__(16) short Ws[128*40];
  int bm = blockIdx.x * 128, bn = blockIdx.y * 128;
  int t = threadIdx.x;
  int row = t >> 1;
  int kseg = (t & 1) * 16;
  int w = t >> 6, lane = t & 63, m16 = lane & 15, q = lane >> 4;
  int wr = (w >> 1)*64, wc = (w & 1)*64;
  floatx4 acc[4][4] = {};
  for (int k0 = 0; k0 < K; k0 += 32){
    if constexpr (sizeof(AT) == 2){
      const short* Ar = (const short*)A + (size_t)(bm + row)*lda + k0 + kseg;
      *(short8*)&As[row*40 + kseg]     = *(const short8*)Ar;
      *(short8*)&As[row*40 + kseg + 8] = *(const short8*)(Ar + 8);
    } else {
      const float* Ar = (const float*)A + (size_t)(bm + row)*lda + k0 + kseg;
      float4 a0 = *(const float4*)Ar;
      float4 a1 = *(const float4*)(Ar + 4);
      float4 a2 = *(const float4*)(Ar + 8);
      float4 a3 = *(const float4*)(Ar + 12);
      short* dst = &As[row*40 + kseg];
      dst[0]=f2bf(a0.x); dst[1]=f2bf(a0.y); dst[2]=f2bf(a0.z); dst[3]=f2bf(a0.w);
      dst[4]=f2bf(a1.x); dst[5]=f2bf(a1.y); dst[6]=f2bf(a1.z); dst[7]=f2bf(a1.w);
      dst[8]=f2bf(a2.x); dst[9]=f2bf(a2.y); dst[10]=f2bf(a2.z); dst[11]=f2bf(a2.w);
      dst[12]=f2bf(a3.x); dst[13]=f2bf(a3.y); dst[14]=f2bf(a3.z); dst[15]=f2bf(a3.w);
    }
    if constexpr (sizeof(WT) == 2){
      const short* Wr = (const short*)W + (size_t)(bn + row)*K + k0 + kseg;
      *(short8*)&Ws[row*40 + kseg]     = *(const short8*)Wr;
      *(short8*)&Ws[row*40 + kseg + 8] = *(const short8*)(Wr + 8);
    } else {
      const float* Wr = (const float*)W + (size_t)(bn + row)*K + k0 + kseg;
      float4 w0 = *(const float4*)Wr;
      float4 w1 = *(const float4*)(Wr + 4);
      float4 w2 = *(const float4*)(Wr + 8);
      float4 w3 = *(const float4*)(Wr + 12);
      short* dst = &Ws[row*40 + kseg];
      dst[0]=f2bf(w0.x); dst[1]=f2bf(w0.y); dst[2]=f2bf(w0.z); dst[3]=f2bf(w0.w);
      dst[4]=f2bf(w1.x); dst[5]=f2bf(w1.y); dst[6]=f2bf(w1.z); dst[7]=f2bf(w1.w);
      dst[8]=f2bf(w2.x); dst[9]=f2bf(w2.y); dst[10]=f2bf(w2.z); dst[11]=f2bf(w2.w);
      dst[12]=f2bf(w3.x); dst[13]=f2bf(w3.y); dst[14]=f2bf(w3.z); dst[15]=f2bf(w3.w);
    }
    __syncthreads();
    short8 af[4];
    #pragma unroll
    for (int i = 0; i < 4; ++i)
      af[i] = *(const short8*)&As[(wr + i*16 + m16)*40 + q*8];
    #pragma unroll
    for (int j = 0; j < 4; ++j){
      short8 bw = *(const short8*)&Ws[(wc + j*16 + m16)*40 + q*8];
      #pragma unroll
      for (int i = 0; i < 4; ++i)
        acc[i][j] = __builtin_amdgcn_mfma_f32_16x16x32_bf16(af[i], bw, acc[i][j], 0, 0, 0);
    }
    __syncthreads();
  }
  #pragma unroll
  for (int j = 0; j < 4; ++j){
    int n = bn + wc + j*16 + m16;
    float bv = bias ? bias[n] : 0.f;
    float gv = 0.f, bbv = 0.f;
    if (ACT == 1){ gv = g[n] * BNS; bbv = bb[n]; }
    #pragma unroll
    for (int i = 0; i < 4; ++i){
      #pragma unroll
      for (int r = 0; r < 4; ++r){
        int m = bm + wr + i*16 + q*4 + r;
        float v = acc[i][j][r] + bv;
        if (ACT == 1){ v = v * gv + bbv; v = fmaxf(v, 0.f); }
        C[(size_t)m*ldc + n] = v;
      }
    }
  }
}

// -------------------------------------------------- encoder max-pools
__global__ __launch_bounds__(256) void maxk_fg(float* __restrict__ f3in){
  int gg = blockIdx.x; int c = threadIdx.x;
  float m = -3e38f;
  for (int k = 0; k < Kn; ++k) m = fmaxf(m, f3in[((size_t)gg*Kn + k)*512 + 256 + c]);
  for (int k = 0; k < Kn; ++k) f3in[((size_t)gg*Kn + k)*512 + c] = m;
}

__global__ __launch_bounds__(384) void maxk_tok(const float* __restrict__ f4, float* __restrict__ tok){
  int gg = blockIdx.x; int c = threadIdx.x;
  float m = -3e38f;
  for (int k = 0; k < Kn; ++k) m = fmaxf(m, f4[((size_t)gg*Kn + k)*DM + c]);
  tok[(size_t)gg*DM + c] = m;
}

// -------------------------------------------------- pos embedding (adds into tok)
__global__ __launch_bounds__(128) void pos_kernel(const float* __restrict__ center,
                                                  const float* __restrict__ w1, const float* __restrict__ b1,
                                                  const float* __restrict__ w2, const float* __restrict__ b2,
                                                  float* __restrict__ tok){
  int gid = blockIdx.x;
  __shared__ float h1[128]; __shared__ float c3[3];
  int t = threadIdx.x;
  if (t < 3) c3[t] = center[(size_t)gid*3 + t];
  __syncthreads();
  float a = w1[t*3+0]*c3[0] + w1[t*3+1]*c3[1] + w1[t*3+2]*c3[2] + b1[t];
  h1[t] = 0.5f * a * (1.f + erff(a * 0.70710678118654752440f));
  __syncthreads();
  for (int c = t; c < DM; c += 128){
    float s = b2[c];
    for (int j = 0; j < 128; ++j) s += w2[(size_t)c*128 + j] * h1[j];
    tok[(size_t)gid*DM + c] += s;
  }
}

// -------------------------------------------------- token gather + res init
__global__ __launch_bounds__(256) void build_h(const float* __restrict__ tok,
                        const int* __restrict__ order,
                        float* __restrict__ h, float* __restrict__ res){
  int i = blockIdx.x * blockDim.x + threadIdx.x;
  if (i >= Bn*Ln*DM) return;
  int c = i % DM; int l = (i / DM) % Ln; int b = i / (DM*Ln);
  int src = order[b*Ln + l];
  src = min(max(src, 0), Gn-1);
  h[i] = tok[((size_t)(b*Gn + src))*DM + c];
  res[i] = 0.f;
}

// -------------------------------------------------- res += h; x = LN(res)*w+b (bf16 out)
__global__ __launch_bounds__(256) void ln_res_kernel(const float* __restrict__ h,
                                                     float* __restrict__ res,
                                                     bf16* __restrict__ x,
                                                     const float* __restrict__ w,
                                                     const float* __restrict__ bias){
  int wv = threadIdx.x >> 6, ln = threadIdx.x & 63;
  int tokid = blockIdx.x*4 + wv;
  const float* hr = h + (size_t)tokid*DM;
  float* rr = res + (size_t)tokid*DM;
  bf16* xr = x + (size_t)tokid*DM;
  float v[6]; float s = 0.f;
  #pragma unroll
  for (int i = 0; i < 6; ++i){ int c = ln + 64*i; float t = hr[c] + rr[c]; rr[c] = t; v[i] = t; s += t; }
  #pragma unroll
  for (int o = 32; o > 0; o >>= 1) s += __shfl_xor(s, o);
  float mu = s * (1.f/DM);
  float q = 0.f;
  #pragma unroll
  for (int i = 0; i < 6; ++i){ float d = v[i] - mu; q += d*d; }
  #pragma unroll
  for (int o = 32; o > 0; o >>= 1) q += __shfl_xor(q, o);
  float rstd = rsqrtf(q * (1.f/DM) + EPSf);
  #pragma unroll
  for (int i = 0; i < 6; ++i){ int c = ln + 64*i;
    xr[c] = __float2bfloat16((v[i]-mu)*rstd*w[c] + bias[c]); }
}

// -------------------------------------------------- conv (big path): xz -> ucv
__global__ __launch_bounds__(256) void conv_fused(const float* __restrict__ xz,
                                                  float* __restrict__ ucv,
                                                  const float* __restrict__ cw,
                                                  const float* __restrict__ cb){
  int blk = blockIdx.x;
  int lc = blk % NLC; int bd = blk / NLC; int dch = bd % 3; int b = bd / 3;
  int t = threadIdx.x; int d = dch*256 + t;
  int l0 = lc*16;
  float w0 = cw[d*4+0], w1 = cw[d*4+1], w2 = cw[d*4+2], w3 = cw[d*4+3];
  float bias = cb[d];
  float u0 = (l0 >= 3) ? xz[((size_t)(b*Ln + l0-3))*1536 + d] : 0.f;
  float u1 = (l0 >= 2) ? xz[((size_t)(b*Ln + l0-2))*1536 + d] : 0.f;
  float u2 = (l0 >= 1) ? xz[((size_t)(b*Ln + l0-1))*1536 + d] : 0.f;
  const float* pin = xz + ((size_t)(b*Ln + l0))*1536 + d;
  float* pout = ucv + ((size_t)(b*Ln + l0))*DI + d;
  float r[16];
  #pragma unroll
  for (int i = 0; i < 16; ++i) r[i] = pin[(size_t)i*1536];
  #pragma unroll
  for (int i = 0; i < 16; ++i){
    float v = u0*w0 + u1*w1 + u2*w2 + r[i]*w3 + bias;
    pout[(size_t)i*DI] = v * fsig(v);
    u0 = u1; u1 = u2; u2 = r[i];
  }
}

// -------------------------------------------------- conv (small path): 2-pass in place
__global__ __launch_bounds__(256) void conv_save(const float* __restrict__ xz,
                                                 float* __restrict__ bnd){
  int blk = blockIdx.x;
  int lc = blk % NLC; int bd = blk / NLC; int dch = bd % 3; int b = bd / 3;
  int t = threadIdx.x; int d = dch*256 + t;
  int l0 = lc*16;
  #pragma unroll
  for (int j = 0; j < 3; ++j){
    int l = l0 - 3 + j;
    float v = (l >= 0) ? xz[((size_t)(b*Ln + l))*1536 + d] : 0.f;
    bnd[(((size_t)blk)*3 + j)*256 + t] = v;
  }
}

__global__ __launch_bounds__(256) void conv_apply(float* __restrict__ xz,
                                                  const float* __restrict__ bnd,
                                                  const float* __restrict__ cw,
                                                  const float* __restrict__ cb){
  int blk = blockIdx.x;
  int lc = blk % NLC; int bd = blk / NLC; int dch = bd % 3; int b = bd / 3;
  int t = threadIdx.x; int d = dch*256 + t;
  int l0 = lc*16;
  float w0 = cw[d*4+0], w1 = cw[d*4+1], w2 = cw[d*4+2], w3 = cw[d*4+3];
  float bias = cb[d];
  float u0 = bnd[(((size_t)blk)*3 + 0)*256 + t];
  float u1 = bnd[(((size_t)blk)*3 + 1)*256 + t];
  float u2 = bnd[(((size_t)blk)*3 + 2)*256 + t];
  float* p = xz + ((size_t)(b*Ln + l0))*1536 + d;
  float r[16];
  #pragma unroll
  for (int i = 0; i < 16; ++i) r[i] = p[(size_t)i*1536];
  #pragma unroll
  for (int i = 0; i < 16; ++i){
    float v = u0*w0 + u1*w1 + u2*w2 + r[i]*w3 + bias;
    p[(size_t)i*1536] = v * fsig(v);
    u0 = u1; u1 = u2; u2 = r[i];
  }
}

// -------------------------------------------------- merged scan (decoupled lookback)
// One dispatch: local scan -> publish (release flag) -> lookback prefix -> final scan.
__global__ __launch_bounds__(256) void scan_one(float* __restrict__ ydst, int ys,
                                                const float* __restrict__ usrc, int uld,
                                                const float* __restrict__ xdb,
                                                const float* __restrict__ dpw,
                                                const float* __restrict__ dpb,
                                                const float* __restrict__ A_log,
                                                const float* __restrict__ Dp,
                                                float* __restrict__ SB_S,
                                                float* __restrict__ SB_dt,
                                                int* __restrict__ flags, int epoch){
  __shared__ float sRow[CHS*56];
  __shared__ float sU[CHS*256];
  int blk = blockIdx.x;
  int c = blk % NCH; int bd = blk / NCH; int dch = bd % 3; int b = bd / 3;
  int t = threadIdx.x; int d = dch*256 + t;
  int l0 = c*CHS;
  for (int i = t; i < CHS*56; i += 256) sRow[i] = xdb[((size_t)(b*Ln + l0))*56 + i];
  const float* up = usrc + ((size_t)(b*Ln + l0))*uld + dch*256;
  #pragma unroll
  for (int i = 0; i < CHS; ++i) sU[i*256 + t] = up[(size_t)i*uld + t];
  float w[DTR];
  const float* wp = dpw + (size_t)d*DTR;
  #pragma unroll
  for (int j = 0; j < DTR; ++j) w[j] = wp[j];
  float a2[DSt], h[DSt];
  const float* ap = A_log + (size_t)d*DSt;
  #pragma unroll
  for (int s = 0; s < DSt; ++s){ a2[s] = -__expf(ap[s]) * LOG2E; h[s] = 0.f; }
  float dbias = dpb[d];
  __syncthreads();
  // pass 1: local scan from h=0 (skip publish only for last chunk's consumers)
  float sumdt = 0.f;
  for (int i = 0; i < CHS; ++i){
    int ro = i*56;
    float dtr = dbias;
    #pragma unroll
    for (int j = 0; j < DTR; ++j) dtr += w[j] * sRow[ro + j];
    float dtv = fsoftplus(dtr);
    sumdt += dtv;
    float du = dtv * sU[i*256 + t];
    #pragma unroll
    for (int s = 0; s < DSt; ++s)
      h[s] = exp2f(dtv * a2[s]) * h[s] + du * sRow[ro + 24 + s];
  }
  if (c < NCH-1){
    size_t sb = ((size_t)blk*256 + t)*16;
    #pragma unroll
    for (int s = 0; s < DSt; ++s) SB_S[sb + s] = h[s];
    SB_dt[(size_t)blk*256 + t] = sumdt;
    __syncthreads();   // drains all waves' stores (vmcnt0 before s_barrier)
    if (t == 0)
      __hip_atomic_store(&flags[blk], epoch, __ATOMIC_RELEASE, __HIP_MEMORY_SCOPE_AGENT);
  }
  // lookback: build h_in from chunks < c (ascending order = exact scanC semantics)
  #pragma unroll
  for (int s = 0; s < DSt; ++s) h[s] = 0.f;
  for (int cc = 0; cc < c; ++cc){
    int fidx = bd*NCH + cc;
    while (__hip_atomic_load(&flags[fidx], __ATOMIC_ACQUIRE, __HIP_MEMORY_SCOPE_AGENT) < epoch)
      __builtin_amdgcn_s_sleep(1);
    size_t base = ((size_t)fidx*256 + t)*16;
    float sd = SB_dt[(size_t)fidx*256 + t];
    #pragma unroll
    for (int s = 0; s < DSt; ++s)
      h[s] = exp2f(sd * a2[s]) * h[s] + SB_S[base + s];
  }
  // pass 2: real scan from h_in, write ungated y
  float Dd = Dp[d];
  float* yp = ydst + ((size_t)(b*Ln + l0))*ys + dch*256;
  for (int i = 0; i < CHS; ++i){
    int ro = i*56;
    float dtr = dbias;
    #pragma unroll
    for (int j = 0; j < DTR; ++j) dtr += w[j] * sRow[ro + j];
    float dtv = fsoftplus(dtr);
    float u = sU[i*256 + t];
    float du = dtv * u;
    float yv = 0.f;
    #pragma unroll
    for (int s = 0; s < DSt; ++s){
      h[s] = exp2f(dtv * a2[s]) * h[s] + du * sRow[ro + 24 + s];
      yv += h[s] * sRow[ro + 40 + s];
    }
    yp[(size_t)i*ys + t] = yv + u*Dd;
  }
}

// -------------------------------------------------- small-path scans (unchanged)
__global__ __launch_bounds__(256) void scanA_kernel(const float* __restrict__ usrc, int uld,
                                                    const float* __restrict__ xdb,
                                                    const float* __restrict__ dpw,
                                                    const float* __restrict__ dpb,
                                                    const float* __restrict__ A_log,
                                                    float* __restrict__ SB_S,
                                                    float* __restrict__ SB_dt){
  __shared__ float sRow[CHS*56];
  __shared__ float sU[CHS*256];
  int blk = blockIdx.x;
  int c = blk % NCH; int bd = blk / NCH; int dch = bd % 3; int b = bd / 3;
  int t = threadIdx.x; int d = dch*256 + t;
  int l0 = c*CHS;
  for (int i = t; i < CHS*56; i += 256) sRow[i] = xdb[((size_t)(b*Ln + l0))*56 + i];
  const float* up = usrc + ((size_t)(b*Ln + l0))*uld + dch*256;
  #pragma unroll
  for (int i = 0; i < CHS; ++i) sU[i*256 + t] = up[(size_t)i*uld + t];
  float w[DTR];
  const float* wp = dpw + (size_t)d*DTR;
  #pragma unroll
  for (int j = 0; j < DTR; ++j) w[j] = wp[j];
  float a2[DSt], h[DSt];
  const float* ap = A_log + (size_t)d*DSt;
  #pragma unroll
  for (int s = 0; s < DSt; ++s){ a2[s] = -__expf(ap[s]) * LOG2E; h[s] = 0.f; }
  float dbias = dpb[d];
  float sumdt = 0.f;
  __syncthreads();
  for (int i = 0; i < CHS; ++i){
    int ro = i*56;
    float dtr = dbias;
    #pragma unroll
    for (int j = 0; j < DTR; ++j) dtr += w[j] * sRow[ro + j];
    float dtv = fsoftplus(dtr);
    sumdt += dtv;
    float du = dtv * sU[i*256 + t];
    #pragma unroll
    for (int s = 0; s < DSt; ++s)
      h[s] = exp2f(dtv * a2[s]) * h[s] + du * sRow[ro + 24 + s];
  }
  size_t sb = ((size_t)blk*256 + t)*16;
  #pragma unroll
  for (int s = 0; s < DSt; ++s) SB_S[sb + s] = h[s];
  SB_dt[(size_t)blk*256 + t] = sumdt;
}

__global__ __launch_bounds__(256) void scanB_kernel(float* __restrict__ ydst_base, int ys,
                                                    const float* __restrict__ usrc, int uld,
                                                    const float* __restrict__ xdb,
                                                    const float* __restrict__ dpw,
                                                    const float* __restrict__ dpb,
                                                    const float* __restrict__ A_log,
                                                    const float* __restrict__ Dp,
                                                    const float* __restrict__ SB_S,
                                                    const float* __restrict__ SB_dt){
  __shared__ float sRow[CHS*56];
  __shared__ float sU[CHS*256];
  int blk = blockIdx.x;
  int c = blk % NCH; int bd = blk / NCH; int dch = bd % 3; int b = bd / 3;
  int t = threadIdx.x; int d = dch*256 + t;
  int l0 = c*CHS;
  for (int i = t; i < CHS*56; i += 256) sRow[i] = xdb[((size_t)(b*Ln + l0))*56 + i];
  const float* up = usrc + ((size_t)(b*Ln + l0))*uld + dch*256;
  #pragma unroll
  for (int i = 0; i < CHS; ++i) sU[i*256 + t] = up[(size_t)i*uld + t];
  float w[DTR];
  const float* wp = dpw + (size_t)d*DTR;
  #pragma unroll
  for (int j = 0; j < DTR; ++j) w[j] = wp[j];
  float a2[DSt], h[DSt];
  const float* ap = A_log + (size_t)d*DSt;
  #pragma unroll
  for (int s = 0; s < DSt; ++s){ a2[s] = -__expf(ap[s]) * LOG2E; h[s] = 0.f; }
  for (int cc = 0; cc < c; ++cc){
    size_t base = (((size_t)bd*NCH + cc)*256 + t)*16;
    float sd = SB_dt[((size_t)bd*NCH + cc)*256 + t];
    #pragma unroll
    for (int s = 0; s < DSt; ++s)
      h[s] = exp2f(sd * a2[s]) * h[s] + SB_S[base + s];
  }
  float dbias = dpb[d];
  float Dd = Dp[d];
  float* ydst = ydst_base + ((size_t)(b*Ln + l0))*ys + dch*256;
  __syncthreads();
  for (int i = 0; i < CHS; ++i){
    int ro = i*56;
    float dtr = dbias;
    #pragma unroll
    for (int j = 0; j < DTR; ++j) dtr += w[j] * sRow[ro + j];
    float dtv = fsoftplus(dtr);
    float u = sU[i*256 + t];
    float du = dtv * u;
    float yv = 0.f;
    #pragma unroll
    for (int s = 0; s < DSt; ++s){
      h[s] = exp2f(dtv * a2[s]) * h[s] + du * sRow[ro + 24 + s];
      yv += h[s] * sRow[ro + 40 + s];
    }
    ydst[(size_t)i*ys + t] = yv + u*Dd;
  }
}

// -------------------------------------------------- final two LayerNorms
__global__ __launch_bounds__(256) void final_ln_kernel(const float* __restrict__ h,
                                                       const float* __restrict__ res,
                                                       const float* w1, const float* b1,
                                                       const float* w2, const float* b2,
                                                       float* __restrict__ x){
  int wv = threadIdx.x >> 6, ln = threadIdx.x & 63;
  int tokid = blockIdx.x*4 + wv;
  const float* hr = h + (size_t)tokid*DM;
  const float* rr = res + (size_t)tokid*DM;
  float* xr = x + (size_t)tokid*DM;
  float v[6]; float s = 0.f;
  #pragma unroll
  for (int i = 0; i < 6; ++i){ int c = ln + 64*i; v[i] = hr[c] + rr[c]; s += v[i]; }
  #pragma unroll
  for (int o = 32; o > 0; o >>= 1) s += __shfl_xor(s, o);
  float mu = s * (1.f/DM); float q = 0.f;
  #pragma unroll
  for (int i = 0; i < 6; ++i){ float dd = v[i]-mu; q += dd*dd; }
  #pragma unroll
  for (int o = 32; o > 0; o >>= 1) q += __shfl_xor(q, o);
  float rstd = rsqrtf(q * (1.f/DM) + EPSf);
  float u[6]; float s2 = 0.f;
  #pragma unroll
  for (int i = 0; i < 6; ++i){ int c = ln + 64*i; u[i] = (v[i]-mu)*rstd*w1[c] + b1[c]; s2 += u[i]; }
  #pragma unroll
  for (int o = 32; o > 0; o >>= 1) s2 += __shfl_xor(s2, o);
  float mu2 = s2 * (1.f/DM); float q2 = 0.f;
  #pragma unroll
  for (int i = 0; i < 6; ++i){ float dd = u[i]-mu2; q2 += dd*dd; }
  #pragma unroll
  for (int o = 32; o > 0; o >>= 1) q2 += __shfl_xor(q2, o);
  float rstd2 = rsqrtf(q2 * (1.f/DM) + EPSf);
  #pragma unroll
  for (int i = 0; i < 6; ++i){ int c = ln + 64*i; xr[c] = (u[i]-mu2)*rstd2*w2[c] + b2[c]; }
}

// -------------------------------------------------- mean over L + MLP head
__global__ __launch_bounds__(384) void head_kernel(const float* __restrict__ x,
    const float* w1, const float* b1, const float* g1, const float* bb1,
    const float* w2, const float* b2, const float* g2, const float* bb2,
    const float* w3, const float* b3, float* __restrict__ out){
  int b = blockIdx.x; int t = threadIdx.x;
  __shared__ float feat[DM]; __shared__ float h1[256]; __shared__ float h2[256];
  float s = 0.f;
  for (int l = 0; l < Ln; ++l) s += x[((size_t)(b*Ln + l))*DM + t];
  feat[t] = s * (1.f/Ln);
  __syncthreads();
  if (t < 256){
    float a = b1[t];
    for (int j = 0; j < DM; ++j) a += w1[(size_t)t*DM + j] * feat[j];
    a = a * (g1[t] * BNS) + bb1[t];
    h1[t] = fmaxf(a, 0.f);
  }
  __syncthreads();
  if (t < 256){
    float a = b2[t];
    for (int j = 0; j < 256; ++j) a += w2[(size_t)t*256 + j] * h1[j];
    a = a * (g2[t] * BNS) + bb2[t];
    h2[t] = fmaxf(a, 0.f);
  }
  __syncthreads();
  if (t < CLSn){
    float a = b3[t];
    for (int j = 0; j < 256; ++j) a += w3[(size_t)t*256 + j] * h2[j];
    out[b*CLSn + t] = a;
  }
}

extern "C" void kernel_launch(void* const* d_in, const int* in_sizes, int n_in,
                              void* d_out, int out_size, void* d_ws, size_t ws_size,
                              hipStream_t stream) {
  if (n_in < 42) return;
  if (out_size < Bn*CLSn) return;
  constexpr size_t WS_FLOATS = 3919936;
  if (ws_size < WS_FLOATS * sizeof(float)) return;
  constexpr size_t MIDF = 5812224;
  constexpr size_t BIGF = 18874368;
  const bool mid = ws_size >= (WS_FLOATS + MIDF) * sizeof(float);
  const bool big = ws_size >= (WS_FLOATS + MIDF + BIGF) * sizeof(float);

  const float* pts       = (const float*)d_in[0];
  const float* enc_w1    = (const float*)d_in[1];  const float* enc_b1    = (const float*)d_in[2];
  const float* enc_bn1_g = (const float*)d_in[3];  const float* enc_bn1_b = (const float*)d_in[4];
  const float* enc_w2    = (const float*)d_in[5];  const float* enc_b2    = (const float*)d_in[6];
  const float* enc_w3    = (const float*)d_in[7];  const float* enc_b3    = (const float*)d_in[8];
  const float* enc_bn2_g = (const float*)d_in[9];  const float* enc_bn2_b = (const float*)d_in[10];
  const float* enc_w4    = (const float*)d_in[11]; const float* enc_b4    = (const float*)d_in[12];
  const float* pos_w1    = (const float*)d_in[13]; const float* pos_b1    = (const float*)d_in[14];
  const float* pos_w2    = (const float*)d_in[15]; const float* pos_b2    = (const float*)d_in[16];
  const float* ln_w      = (const float*)d_in[17]; const float* ln_b      = (const float*)d_in[18];
  const float* in_proj_w = (const float*)d_in[19];
  const float* conv_w    = (const float*)d_in[20]; const float* conv_b    = (const float*)d_in[21];
  const float* x_proj_w  = (const float*)d_in[22];
  const float* dt_proj_w = (const float*)d_in[23]; const float* dt_proj_b = (const float*)d_in[24];
  const float* A_log     = (const float*)d_in[25]; const float* D_param   = (const float*)d_in[26];
  const float* out_proj_w= (const float*)d_in[27];
  const float* normf_w   = (const float*)d_in[28]; const float* normf_b   = (const float*)d_in[29];
  const float* norm_w    = (const float*)d_in[30]; const float* norm_b    = (const float*)d_in[31];
  const float* head_w1   = (const float*)d_in[32]; const float* head_b1   = (const float*)d_in[33];
  const float* head_bn1_g= (const float*)d_in[34]; const float* head_bn1_b= (const float*)d_in[35];
  const float* head_w2   = (const float*)d_in[36]; const float* head_b2   = (const float*)d_in[37];
  const float* head_bn2_g= (const float*)d_in[38]; const float* head_bn2_b= (const float*)d_in[39];
  const float* head_w3   = (const float*)d_in[40]; const float* head_b3   = (const float*)d_in[41];

  float* ws = (float*)d_ws;
  float* hb   = ws;
  float* resb = ws + 589824;
  float* U    = ws + 1179648;
  float* center = U;
  float* nb     = U + 1536;
  float* tok    = U + 50688;
  int*   order  = (int*)(U + 247296);
  float* eb0    = U + 262144;
  float* eb1    = U + 1310720;
  float* xz   = U;
  float* xdb  = U + 2359296;
  bf16*  xb   = (bf16*)(U + 2445312);
  float* SBdt_s = U + 2445312;
  float* BND  = U + 2482176;
  float* SBS_s  = hb;
  float* xf   = U;
  float* WB = ws + WS_FLOATS;
  bf16* wb_ip = (bf16*)WB;
  bf16* wb_op = (bf16*)(WB + 3538944);
  bf16* wb_xp = (bf16*)(WB + 5308416);
  bf16* wb_e2 = (bf16*)(WB + 5566464);
  bf16* wb_e3 = (bf16*)(WB + 5582848);
  bf16* wb_e4 = (bf16*)(WB + 5713920);
  float* F3in = WB + MIDF;
  float* F3   = WB + MIDF + 8388608;
  float* F1   = WB + MIDF + 16777216;
  float* F4   = F3in;
  float* ucv  = F3in;
  float* SBS_b  = F3;                 // 144*256*16 = 589,824 floats
  float* SBdt_b = F1;                 // 36,864 floats
  int* flags    = (int*)(F1 + 36864); // 144 ints, untouched elsewhere

  if (mid)
    cvt_all<<<11352, 256, 0, stream>>>(in_proj_w, out_proj_w, x_proj_w,
                                       enc_w2, enc_w3, enc_w4, (bf16*)WB);
  if (big)
    zero_flags<<<1, 256, 0, stream>>>(flags);

  fps_kernel<<<Bn, 64, 0, stream>>>(pts, center, order);
  knn_kernel<<<Bn*Gn, 256, 0, stream>>>(pts, center, nb);

  if (big){
    gemm_mfma<float,float,1,0><<<dim3(256,2), 256, 0, stream>>>(nb, 3, enc_w1, enc_b1,
        enc_bn1_g, enc_bn1_b, F1 + 65536, 128, 16384, 128, 3);
    gemm_mfma_128<float,bf16,0><<<dim3(128,2), 256, 0, stream>>>(F1 + 65536, 128, wb_e2, enc_b2,
        nullptr, nullptr, F3in + 256, 512, 16384, 256, 128);
    maxk_fg<<<512, 256, 0, stream>>>(F3in);
    gemm_mfma_128<float,bf16,1><<<dim3(128,4), 256, 0, stream>>>(F3in, 512, wb_e3, enc_b3,
        enc_bn2_g, enc_bn2_b, F3, 512, 16384, 512, 512);
    gemm_mfma_128<float,bf16,0><<<dim3(128,3), 256, 0, stream>>>(F3, 512, wb_e4, enc_b4,
        nullptr, nullptr, F4, 384, 16384, 384, 512);
    maxk_tok<<<512, 384, 0, stream>>>(F4, tok);
  } else {
    for (int ch = 0; ch < 8; ++ch){
      const float* nb_c = nb + (size_t)ch*2048*3;
      float* tok_c = tok + (size_t)ch*64*DM;
      gemm_mfma<float,float,1,0><<<dim3(32,2), 256, 0, stream>>>(nb_c, 3, enc_w1, enc_b1,
          enc_bn1_g, enc_bn1_b, eb1, 128, 2048, 128, 3);
      if (mid){
        gemm_mfma_128<float,bf16,0><<<dim3(16,2), 256, 0, stream>>>(eb1, 128, wb_e2, enc_b2,
            nullptr, nullptr, eb0 + 256, 512, 2048, 256, 128);
        maxk_fg<<<64, 256, 0, stream>>>(eb0);
        gemm_mfma_128<float,bf16,1><<<dim3(16,4), 256, 0, stream>>>(eb0, 512, wb_e3, enc_b3,
            enc_bn2_g, enc_bn2_b, eb1, 512, 2048, 512, 512);
        gemm_mfma_128<float,bf16,0><<<dim3(16,3), 256, 0, stream>>>(eb1, 512, wb_e4, enc_b4,
            nullptr, nullptr, eb0, 384, 2048, 384, 512);
      } else {
        gemm_mfma_128<float,float,0><<<dim3(16,2), 256, 0, stream>>>(eb1, 128, enc_w2, enc_b2,
            nullptr, nullptr, eb0 + 256, 512, 2048, 256, 128);
        maxk_fg<<<64, 256, 0, stream>>>(eb0);
        gemm_mfma_128<float,float,1><<<dim3(16,4), 256, 0, stream>>>(eb0, 512, enc_w3, enc_b3,
            enc_bn2_g, enc_bn2_b, eb1, 512, 2048, 512, 512);
        gemm_mfma_128<float,float,0><<<dim3(16,3), 256, 0, stream>>>(eb1, 512, enc_w4, enc_b4,
            nullptr, nullptr, eb0, 384, 2048, 384, 512);
      }
      maxk_tok<<<64, 384, 0, stream>>>(eb0, tok_c);
    }
  }

  pos_kernel<<<Bn*Gn, 128, 0, stream>>>(center, pos_w1, pos_b1, pos_w2, pos_b2, tok);
  build_h<<<(Bn*Ln*DM + 255)/256, 256, 0, stream>>>(tok, order, hb, resb);

  for (int l = 0; l < DEPTH; ++l){
    const float* lnw  = ln_w      + (size_t)l*DM;
    const float* lnb  = ln_b      + (size_t)l*DM;
    const float* ipw  = in_proj_w + (size_t)l*1536*DM;
    const float* cw   = conv_w    + (size_t)l*DI*4;
    const float* cb   = conv_b    + (size_t)l*DI;
    const float* xpw  = x_proj_w  + (size_t)l*56*DI;
    const float* dpw  = dt_proj_w + (size_t)l*DI*DTR;
    const float* dpb  = dt_proj_b + (size_t)l*DI;
    const float* Alg  = A_log     + (size_t)l*DI*DSt;
    const float* Dpar = D_param   + (size_t)l*DI;
    const float* opw  = out_proj_w+ (size_t)l*DM*DI;

    ln_res_kernel<<<Bn*Ln/4, 256, 0, stream>>>(hb, resb, xb, lnw, lnb);
    if (mid){
      gemm_mfma<bf16,bf16,0,0><<<dim3(24,24), 256, 0, stream>>>(xb, DM,
          wb_ip + (size_t)l*1536*DM, nullptr, nullptr, nullptr, xz, 1536, Bn*Ln, 1536, DM);
    } else {
      gemm_mfma<bf16,float,0,0><<<dim3(24,24), 256, 0, stream>>>(xb, DM, ipw,
          nullptr, nullptr, nullptr, xz, 1536, Bn*Ln, 1536, DM);
    }
    if (big){
      conv_fused<<<Bn*3*NLC, 256, 0, stream>>>(xz, ucv, cw, cb);
      if (mid)
        gemm_mfma<float,bf16,0,0><<<dim3(24,1), 256, 0, stream>>>(ucv, DI,
            wb_xp + (size_t)l*56*DI, nullptr, nullptr, nullptr, xdb, 56, Bn*Ln, 56, DI);
      else
        gemm_mfma<float,float,0,0><<<dim3(24,1), 256, 0, stream>>>(ucv, DI, xpw,
            nullptr, nullptr, nullptr, xdb, 56, Bn*Ln, 56, DI);
      scan_one<<<Bn*3*NCH, 256, 0, stream>>>(xz, 1536, ucv, DI, xdb, dpw, dpb,
          Alg, Dpar, SBS_b, SBdt_b, flags, l + 1);
    } else {
      conv_save<<<Bn*3*NLC, 256, 0, stream>>>(xz, BND);
      conv_apply<<<Bn*3*NLC, 256, 0, stream>>>(xz, BND, cw, cb);
      if (mid)
        gemm_mfma<float,bf16,0,0><<<dim3(24,1), 256, 0, stream>>>(xz, 1536,
            wb_xp + (size_t)l*56*DI, nullptr, nullptr, nullptr, xdb, 56, Bn*Ln, 56, DI);
      else
        gemm_mfma<float,float,0,0><<<dim3(24,1), 256, 0, stream>>>(xz, 1536, xpw,
            nullptr, nullptr, nullptr, xdb, 56, Bn*Ln, 56, DI);
      scanA_kernel<<<Bn*3*NCH, 256, 0, stream>>>(xz, 1536, xdb, dpw, dpb, Alg, SBS_s, SBdt_s);
      scanB_kernel<<<Bn*3*NCH, 256, 0, stream>>>(xz, 1536, xz, 1536,
          xdb, dpw, dpb, Alg, Dpar, SBS_s, SBdt_s);
    }
    if (mid){
      gemm_mfma<float,bf16,0,1><<<dim3(24,6), 256, 0, stream>>>(xz, 1536,
          wb_op + (size_t)l*DM*DI, nullptr, xz, nullptr, hb, DM, Bn*Ln, DM, DI);
    } else {
      gemm_mfma<float,float,0,1><<<dim3(24,6), 256, 0, stream>>>(xz, 1536, opw,
          nullptr, xz, nullptr, hb, DM, Bn*Ln, DM, DI);
    }
  }

  final_ln_kernel<<<Bn*Ln/4, 256, 0, stream>>>(hb, resb, normf_w, normf_b, norm_w, norm_b, xf);
  head_kernel<<<Bn, 384, 0, stream>>>(xf, head_w1, head_b1, head_bn1_g, head_bn1_b,
                                      head_w2, head_b2, head_bn2_g, head_bn2_b,
                                      head_w3, head_b3, (float*)d_out);
}

// Round 14
// 1759.169 us; speedup vs baseline: 1.1850x; 1.1850x over previous
//
#include <hip/hip_runtime.h>
#include <hip/hip_bf16.h>

using bf16 = __hip_bfloat16;
using short8  = __attribute__((ext_vector_type(8))) short;
using floatx4 = __attribute__((ext_vector_type(4))) float;
using ull = unsigned long long;

constexpr int Bn = 4, Np = 1024, Gn = 128, Kn = 32;
constexpr int DM = 384, DEPTH = 12, CLSn = 40;
constexpr int DI = 768, DSt = 16, DTR = 24;
constexpr int Ln = 384;
constexpr int NCH = 12, CHS = 32;      // scan: 12 chunks x 32 steps
constexpr int NLC = 24;                // conv: 24 chunks x 16 steps
constexpr float EPSf = 1e-5f;
constexpr float BNS = 0.99999500003749968752f; // 1/sqrt(1+1e-5)
constexpr float LOG2E = 1.4426950408889634f;

static __device__ __forceinline__ short f2bf(float f){
  bf16 h = __float2bfloat16(f);
  return *reinterpret_cast<short*>(&h);
}
static __device__ __forceinline__ float fsig(float x){ return 1.f/(1.f + __expf(-x)); }
static __device__ __forceinline__ float fsoftplus(float x){
  return fmaxf(x, 0.f) + __logf(1.f + __expf(-fabsf(x)));
}

// DPP lane move (VALU-latency). bound_ctrl=true -> invalid lanes read 0.
template<int CTRL>
static __device__ __forceinline__ int dppmov(int x){
  return __builtin_amdgcn_update_dpp(0, x, CTRL, 0xF, 0xF, true);
}
// 64-bit unsigned max reduce to lane 63 via DPP.
static __device__ __forceinline__ ull redmax64(ull key){
  #define RSTEP(CTRL) { \
    int hi = (int)(unsigned)(key >> 32), lo = (int)(unsigned)key; \
    int h2 = dppmov<CTRL>(hi), l2 = dppmov<CTRL>(lo); \
    ull k2 = ((ull)(unsigned)h2 << 32) | (unsigned)l2; \
    if (k2 > key) key = k2; }
  RSTEP(0x111) RSTEP(0x112) RSTEP(0x114) RSTEP(0x118) RSTEP(0x142) RSTEP(0x143)
  #undef RSTEP
  return key;
}

// ---------------------------------------------------------------- FPS
// Single wave. Coordinates + dmin in REGISTERS for the distance chain; LDS copy
// kept only for the wave-uniform winner lookup (broadcast read).
// key = (dist_bits<<32)|(1023-n): argmax, tie -> lowest n (np.argmax).
__global__ __launch_bounds__(64) void fps_kernel(const float* __restrict__ pts,
                                                 float* __restrict__ center){
  int b = blockIdx.x, t = threadIdx.x;
  __shared__ float xs[1024], ys[1024], zs[1024];
  const float* p = pts + (size_t)b * Np * 3;
  float X[16], Y[16], Z[16], D[16];
  #pragma unroll
  for (int i = 0; i < 16; ++i){
    int n = t + 64*i;
    float a = p[n*3+0], c = p[n*3+1], e = p[n*3+2];
    X[i] = a; Y[i] = c; Z[i] = e;
    xs[n] = a; ys[n] = c; zs[n] = e;
    D[i] = 1e10f;
  }
  __syncthreads();
  float px = xs[0], py = ys[0], pz = zs[0];
  if (t == 0){
    center[(size_t)(b*Gn)*3+0] = px;
    center[(size_t)(b*Gn)*3+1] = py;
    center[(size_t)(b*Gn)*3+2] = pz;
  }
  for (int it = 1; it < Gn; ++it){
    float v = -1.f; int nbest = t;
    #pragma unroll
    for (int i = 0; i < 16; ++i){
      float dx = __fsub_rn(X[i], px);
      float dy = __fsub_rn(Y[i], py);
      float dz = __fsub_rn(Z[i], pz);
      float d  = __fadd_rn(__fadd_rn(__fmul_rn(dx,dx), __fmul_rn(dy,dy)), __fmul_rn(dz,dz));
      float dm = fminf(D[i], d); D[i] = dm;
      if (dm > v){ v = dm; nbest = t + 64*i; }  // ascending n: lowest n on tie
    }
    ull key = ((ull)__float_as_uint(v) << 32) | (unsigned)(Np-1 - nbest);
    key = redmax64(key);
    int lo63 = __builtin_amdgcn_readlane((int)(unsigned)(key & 0xFFFFFFFFu), 63);
    int wn = Np-1 - lo63;
    wn = min(max(wn, 0), Np-1);           // wave-uniform
    px = xs[wn]; py = ys[wn]; pz = zs[wn]; // broadcast reads
    if (t == 0){
      center[(size_t)(b*Gn+it)*3+0] = px;
      center[(size_t)(b*Gn+it)*3+1] = py;
      center[(size_t)(b*Gn+it)*3+2] = pz;
    }
  }
}

// ---------------------------------------------------------------- KNN
__global__ __launch_bounds__(256) void knn_kernel(const float* __restrict__ pts,
                                                  const float* __restrict__ center,
                                                  float* __restrict__ nb){
  int gid = blockIdx.x; int b = gid >> 7;
  __shared__ float d2[1024];
  __shared__ float rv[4]; __shared__ int ri[4];
  int t = threadIdx.x;
  float cx = center[(size_t)gid*3+0], cy = center[(size_t)gid*3+1], cz = center[(size_t)gid*3+2];
  const float* p = pts + (size_t)b * Np * 3;
  for (int n = t; n < Np; n += 256){
    float dx = __fsub_rn(cx, p[n*3+0]);
    float dy = __fsub_rn(cy, p[n*3+1]);
    float dz = __fsub_rn(cz, p[n*3+2]);
    d2[n] = __fadd_rn(__fadd_rn(__fmul_rn(dx,dx), __fmul_rn(dy,dy)), __fmul_rn(dz,dz));
  }
  __syncthreads();
  for (int kk = 0; kk < Kn; ++kk){
    float v = 3e38f; int idx = 0;
    for (int n = t; n < Np; n += 256){
      float d = d2[n];
      if (d < v || (d == v && n < idx)){ v = d; idx = n; }
    }
    ull key = ((ull)(unsigned)(~__float_as_uint(v)) << 32) | (unsigned)(Np-1 - idx);
    key = redmax64(key);
    if ((t & 63) == 63){
      rv[t>>6] = __uint_as_float(~(unsigned)(key >> 32));
      ri[t>>6] = Np-1 - (int)(unsigned)(key & 0xFFFFFFFFu);
    }
    __syncthreads();
    if (t == 0){
      float bv = rv[0]; int bi = ri[0];
      for (int w = 1; w < 4; ++w){
        if (rv[w] < bv || (rv[w] == bv && ri[w] < bi)){ bv = rv[w]; bi = ri[w]; }
      }
      bi = min(max(bi, 0), Np-1);
      nb[((size_t)gid*Kn+kk)*3+0] = __fsub_rn(p[bi*3+0], cx);
      nb[((size_t)gid*Kn+kk)*3+1] = __fsub_rn(p[bi*3+1], cy);
      nb[((size_t)gid*Kn+kk)*3+2] = __fsub_rn(p[bi*3+2], cz);
      d2[bi] = 3e38f;
    }
    __syncthreads();
  }
}

// ---------------------------------------------------------------- all weight conversions, one dispatch
// dst segments are contiguous in WB (bf16 elements): [ip 7077888 | op 3538944 |
// xp 516096 | e2 32768 | e3 262144 | e4 196608] = 11,624,448 total.
__global__ __launch_bounds__(256) void cvt_all(const float* __restrict__ s0,
    const float* __restrict__ s1, const float* __restrict__ s2,
    const float* __restrict__ s3, const float* __restrict__ s4,
    const float* __restrict__ s5, bf16* __restrict__ dst){
  long i = ((long)blockIdx.x*256 + threadIdx.x)*4;
  if (i >= 11624448L) return;
  const float* s; long off;
  if      (i <  7077888L){ s = s0; off = 0L; }
  else if (i < 10616832L){ s = s1; off =  7077888L; }
  else if (i < 11132928L){ s = s2; off = 10616832L; }
  else if (i < 11165696L){ s = s3; off = 11132928L; }
  else if (i < 11427840L){ s = s4; off = 11165696L; }
  else                   { s = s5; off = 11427840L; }
  float4 v = *(const float4*)(s + (i - off));
  short* o = (short*)dst + i;
  o[0] = f2bf(v.x); o[1] = f2bf(v.y); o[2] = f2bf(v.z); o[3] = f2bf(v.w);
}

// ---------------------------------------------------------------- MFMA GEMM 64x64
// MODE 0: plain A. MODE 1 (GATE): A = y (lda), z via gz pointer (stride 1536, col+768),
//   element = y * silu(z).
template<typename AT, typename WT, int ACT, int MODE>
__global__ __launch_bounds__(256) void gemm_mfma(const AT* __restrict__ A, int lda,
                                                 const WT* __restrict__ W,
                                                 const float* __restrict__ bias,
                                                 const float* __restrict__ gz,
                                                 const float* __restrict__ bbp,
                                                 float* __restrict__ C, int ldc,
                                                 int M, int N, int K){
  __shared__ __align__(16) short As[64*40];
  __shared__ __align__(16) short Ws[64*40];
  int bm = blockIdx.x * 64, bn = blockIdx.y * 64;
  int t = threadIdx.x;
  int row = t >> 2;
  int kseg = (t & 3) * 8;
  int w = t >> 6, lane = t & 63, m16 = lane & 15, q = lane >> 4;
  bool kvec = ((K & 3) == 0) && ((lda & 3) == 0 || sizeof(AT) == 2);
  floatx4 acc[4] = {};
  for (int k0 = 0; k0 < K; k0 += 32){
    // ---- A staging
    if constexpr (MODE == 1){
      const float* Yr = (const float*)A + (size_t)(bm + row)*lda + k0 + kseg;
      const float* Zr = gz + (size_t)(bm + row)*1536 + 768 + k0 + kseg;
      float y[8], z[8];
      *(float4*)&y[0] = *(const float4*)Yr;  *(float4*)&y[4] = *(const float4*)(Yr + 4);
      *(float4*)&z[0] = *(const float4*)Zr;  *(float4*)&z[4] = *(const float4*)(Zr + 4);
      short* dst = &As[row*40 + kseg];
      #pragma unroll
      for (int jj = 0; jj < 8; ++jj) dst[jj] = f2bf(y[jj] * (z[jj] * fsig(z[jj])));
    } else if constexpr (sizeof(AT) == 2){
      *(short8*)&As[row*40 + kseg] =
          *(const short8*)((const short*)A + (size_t)(bm + row)*lda + k0 + kseg);
    } else {
      const float* Ar = (const float*)A + (size_t)(bm + row)*lda;
      short* dst = &As[row*40 + kseg];
      if (kvec && (k0 + kseg + 8 <= K)){
        float4 a0 = *(const float4*)(Ar + k0 + kseg);
        float4 a1 = *(const float4*)(Ar + k0 + kseg + 4);
        dst[0]=f2bf(a0.x); dst[1]=f2bf(a0.y); dst[2]=f2bf(a0.z); dst[3]=f2bf(a0.w);
        dst[4]=f2bf(a1.x); dst[5]=f2bf(a1.y); dst[6]=f2bf(a1.z); dst[7]=f2bf(a1.w);
      } else {
        #pragma unroll
        for (int j = 0; j < 8; ++j){
          int k = k0 + kseg + j;
          dst[j] = (k < K) ? f2bf(Ar[k]) : (short)0;
        }
      }
    }
    // ---- W staging
    if constexpr (sizeof(WT) == 2){
      int n = bn + row;
      short8 v;
      #pragma unroll
      for (int j = 0; j < 8; ++j) v[j] = 0;
      if (n < N) v = *(const short8*)((const short*)W + (size_t)n*K + k0 + kseg);
      *(short8*)&Ws[row*40 + kseg] = v;
    } else {
      int n = bn + row;
      short* dst = &Ws[row*40 + kseg];
      if (n < N && ((K & 3) == 0) && (k0 + kseg + 8 <= K)){
        const float* Wr = (const float*)W + (size_t)n*K + k0 + kseg;
        float4 w0 = *(const float4*)Wr;
        float4 w1 = *(const float4*)(Wr + 4);
        dst[0]=f2bf(w0.x); dst[1]=f2bf(w0.y); dst[2]=f2bf(w0.z); dst[3]=f2bf(w0.w);
        dst[4]=f2bf(w1.x); dst[5]=f2bf(w1.y); dst[6]=f2bf(w1.z); dst[7]=f2bf(w1.w);
      } else {
        #pragma unroll
        for (int j = 0; j < 8; ++j){
          int k = k0 + kseg + j;
          dst[j] = (n < N && k < K) ? f2bf(((const float*)W)[(size_t)n*K + k]) : (short)0;
        }
      }
    }
    __syncthreads();
    short8 af = *(const short8*)&As[(w*16 + m16)*40 + q*8];
    #pragma unroll
    for (int j = 0; j < 4; ++j){
      short8 bfr = *(const short8*)&Ws[(j*16 + m16)*40 + q*8];
      acc[j] = __builtin_amdgcn_mfma_f32_16x16x32_bf16(af, bfr, acc[j], 0, 0, 0);
    }
    __syncthreads();
  }
  #pragma unroll
  for (int j = 0; j < 4; ++j){
    int n = bn + j*16 + m16;
    if (n < N){
      float bv = bias ? bias[n] : 0.f;
      float gv = 0.f, bbv = 0.f;
      if (ACT == 1){ gv = gz[n] * BNS; bbv = bbp[n]; }
      #pragma unroll
      for (int r = 0; r < 4; ++r){
        int m = bm + w*16 + q*4 + r;
        float v = acc[j][r] + bv;
        if (ACT == 1){ v = v * gv + bbv; v = fmaxf(v, 0.f); }
        C[(size_t)m*ldc + n] = v;
      }
    }
  }
}

// -------------------------------------------------- encoder max-pools
__global__ __launch_bounds__(256) void maxk_fg(float* __restrict__ f3in){
  int gg = blockIdx.x; int c = threadIdx.x;
  float m = -3e38f;
  for (int k = 0; k < Kn; ++k) m = fmaxf(m, f3in[((size_t)gg*Kn + k)*512 + 256 + c]);
  for (int k = 0; k < Kn; ++k) f3in[((size_t)gg*Kn + k)*512 + c] = m;
}

__global__ __launch_bounds__(384) void maxk_tok(const float* __restrict__ f4, float* __restrict__ tok){
  int gg = blockIdx.x; int c = threadIdx.x;
  float m = -3e38f;
  for (int k = 0; k < Kn; ++k) m = fmaxf(m, f4[((size_t)gg*Kn + k)*DM + c]);
  tok[(size_t)gg*DM + c] = m;
}

// -------------------------------------------------- pos embedding (adds into tok)
__global__ __launch_bounds__(128) void pos_kernel(const float* __restrict__ center,
                                                  const float* __restrict__ w1, const float* __restrict__ b1,
                                                  const float* __restrict__ w2, const float* __restrict__ b2,
                                                  float* __restrict__ tok){
  int gid = blockIdx.x;
  __shared__ float h1[128]; __shared__ float c3[3];
  int t = threadIdx.x;
  if (t < 3) c3[t] = center[(size_t)gid*3 + t];
  __syncthreads();
  float a = w1[t*3+0]*c3[0] + w1[t*3+1]*c3[1] + w1[t*3+2]*c3[2] + b1[t];
  h1[t] = 0.5f * a * (1.f + erff(a * 0.70710678118654752440f));
  __syncthreads();
  for (int c = t; c < DM; c += 128){
    float s = b2[c];
    for (int j = 0; j < 128; ++j) s += w2[(size_t)c*128 + j] * h1[j];
    tok[(size_t)gid*DM + c] += s;
  }
}

// -------------------------------------------------- stable argsort (rank count)
__global__ __launch_bounds__(128) void sort_kernel(const float* __restrict__ center,
                                                   int* __restrict__ order){
  int bax = blockIdx.x; int b = bax / 3, ax = bax % 3;
  __shared__ float key[128];
  int t = threadIdx.x;
  key[t] = center[(size_t)(b*Gn + t)*3 + ax];
  __syncthreads();
  float kt = key[t]; int r = 0;
  for (int j = 0; j < Gn; ++j){
    float kj = key[j];
    r += (kj < kt || (kj == kt && j < t)) ? 1 : 0;
  }
  r = min(max(r, 0), Gn-1);
  order[b*Ln + ax*Gn + r] = t;
}

// -------------------------------------------------- token gather + res init
__global__ __launch_bounds__(256) void build_h(const float* __restrict__ tok,
                        const int* __restrict__ order,
                        float* __restrict__ h, float* __restrict__ res){
  int i = blockIdx.x * blockDim.x + threadIdx.x;
  if (i >= Bn*Ln*DM) return;
  int c = i % DM; int l = (i / DM) % Ln; int b = i / (DM*Ln);
  int src = order[b*Ln + l];
  src = min(max(src, 0), Gn-1);
  h[i] = tok[((size_t)(b*Gn + src))*DM + c];
  res[i] = 0.f;
}

// -------------------------------------------------- res += h; x = LN(res)*w+b (bf16 out)
__global__ __launch_bounds__(256) void ln_res_kernel(const float* __restrict__ h,
                                                     float* __restrict__ res,
                                                     bf16* __restrict__ x,
                                                     const float* __restrict__ w,
                                                     const float* __restrict__ bias){
  int wv = threadIdx.x >> 6, ln = threadIdx.x & 63;
  int tokid = blockIdx.x*4 + wv;
  const float* hr = h + (size_t)tokid*DM;
  float* rr = res + (size_t)tokid*DM;
  bf16* xr = x + (size_t)tokid*DM;
  float v[6]; float s = 0.f;
  #pragma unroll
  for (int i = 0; i < 6; ++i){ int c = ln + 64*i; float t = hr[c] + rr[c]; rr[c] = t; v[i] = t; s += t; }
  #pragma unroll
  for (int o = 32; o > 0; o >>= 1) s += __shfl_xor(s, o);
  float mu = s * (1.f/DM);
  float q = 0.f;
  #pragma unroll
  for (int i = 0; i < 6; ++i){ float d = v[i] - mu; q += d*d; }
  #pragma unroll
  for (int o = 32; o > 0; o >>= 1) q += __shfl_xor(q, o);
  float rstd = rsqrtf(q * (1.f/DM) + EPSf);
  #pragma unroll
  for (int i = 0; i < 6; ++i){ int c = ln + 64*i;
    xr[c] = __float2bfloat16((v[i]-mu)*rstd*w[c] + bias[c]); }
}

// -------------------------------------------------- conv (big path): xz -> ucv
__global__ __launch_bounds__(256) void conv_fused(const float* __restrict__ xz,
                                                  float* __restrict__ ucv,
                                                  const float* __restrict__ cw,
                                                  const float* __restrict__ cb){
  int blk = blockIdx.x;
  int lc = blk % NLC; int bd = blk / NLC; int dch = bd % 3; int b = bd / 3;
  int t = threadIdx.x; int d = dch*256 + t;
  int l0 = lc*16;
  float w0 = cw[d*4+0], w1 = cw[d*4+1], w2 = cw[d*4+2], w3 = cw[d*4+3];
  float bias = cb[d];
  float u0 = (l0 >= 3) ? xz[((size_t)(b*Ln + l0-3))*1536 + d] : 0.f;
  float u1 = (l0 >= 2) ? xz[((size_t)(b*Ln + l0-2))*1536 + d] : 0.f;
  float u2 = (l0 >= 1) ? xz[((size_t)(b*Ln + l0-1))*1536 + d] : 0.f;
  const float* pin = xz + ((size_t)(b*Ln + l0))*1536 + d;
  float* pout = ucv + ((size_t)(b*Ln + l0))*DI + d;
  float r[16];
  #pragma unroll
  for (int i = 0; i < 16; ++i) r[i] = pin[(size_t)i*1536];
  #pragma unroll
  for (int i = 0; i < 16; ++i){
    float v = u0*w0 + u1*w1 + u2*w2 + r[i]*w3 + bias;
    pout[(size_t)i*DI] = v * fsig(v);
    u0 = u1; u1 = u2; u2 = r[i];
  }
}

// -------------------------------------------------- conv (small path): 2-pass in place
__global__ __launch_bounds__(256) void conv_save(const float* __restrict__ xz,
                                                 float* __restrict__ bnd){
  int blk = blockIdx.x;
  int lc = blk % NLC; int bd = blk / NLC; int dch = bd % 3; int b = bd / 3;
  int t = threadIdx.x; int d = dch*256 + t;
  int l0 = lc*16;
  #pragma unroll
  for (int j = 0; j < 3; ++j){
    int l = l0 - 3 + j;
    float v = (l >= 0) ? xz[((size_t)(b*Ln + l))*1536 + d] : 0.f;
    bnd[(((size_t)blk)*3 + j)*256 + t] = v;
  }
}

__global__ __launch_bounds__(256) void conv_apply(float* __restrict__ xz,
                                                  const float* __restrict__ bnd,
                                                  const float* __restrict__ cw,
                                                  const float* __restrict__ cb){
  int blk = blockIdx.x;
  int lc = blk % NLC; int bd = blk / NLC; int dch = bd % 3; int b = bd / 3;
  int t = threadIdx.x; int d = dch*256 + t;
  int l0 = lc*16;
  float w0 = cw[d*4+0], w1 = cw[d*4+1], w2 = cw[d*4+2], w3 = cw[d*4+3];
  float bias = cb[d];
  float u0 = bnd[(((size_t)blk)*3 + 0)*256 + t];
  float u1 = bnd[(((size_t)blk)*3 + 1)*256 + t];
  float u2 = bnd[(((size_t)blk)*3 + 2)*256 + t];
  float* p = xz + ((size_t)(b*Ln + l0))*1536 + d;
  float r[16];
  #pragma unroll
  for (int i = 0; i < 16; ++i) r[i] = p[(size_t)i*1536];
  #pragma unroll
  for (int i = 0; i < 16; ++i){
    float v = u0*w0 + u1*w1 + u2*w2 + r[i]*w3 + bias;
    p[(size_t)i*1536] = v * fsig(v);
    u0 = u1; u1 = u2; u2 = r[i];
  }
}

// -------------------------------------------------- chunked selective scan
__global__ __launch_bounds__(256) void scanA_kernel(const float* __restrict__ usrc, int uld,
                                                    const float* __restrict__ xdb,
                                                    const float* __restrict__ dpw,
                                                    const float* __restrict__ dpb,
                                                    const float* __restrict__ A_log,
                                                    float* __restrict__ SB_S,
                                                    float* __restrict__ SB_dt){
  __shared__ float sRow[CHS*56];
  __shared__ float sU[CHS*256];
  int blk = blockIdx.x;
  int c = blk % NCH; int bd = blk / NCH; int dch = bd % 3; int b = bd / 3;
  int t = threadIdx.x; int d = dch*256 + t;
  int l0 = c*CHS;
  for (int i = t; i < CHS*56; i += 256) sRow[i] = xdb[((size_t)(b*Ln + l0))*56 + i];
  const float* up = usrc + ((size_t)(b*Ln + l0))*uld + dch*256;
  #pragma unroll
  for (int i = 0; i < CHS; ++i) sU[i*256 + t] = up[(size_t)i*uld + t];
  float w[DTR];
  const float* wp = dpw + (size_t)d*DTR;
  #pragma unroll
  for (int j = 0; j < DTR; ++j) w[j] = wp[j];
  float a2[DSt], h[DSt];
  const float* ap = A_log + (size_t)d*DSt;
  #pragma unroll
  for (int s = 0; s < DSt; ++s){ a2[s] = -__expf(ap[s]) * LOG2E; h[s] = 0.f; }
  float dbias = dpb[d];
  float sumdt = 0.f;
  __syncthreads();
  for (int i = 0; i < CHS; ++i){
    int ro = i*56;
    float dtr = dbias;
    #pragma unroll
    for (int j = 0; j < DTR; ++j) dtr += w[j] * sRow[ro + j];
    float dtv = fsoftplus(dtr);
    sumdt += dtv;
    float du = dtv * sU[i*256 + t];
    #pragma unroll
    for (int s = 0; s < DSt; ++s)
      h[s] = exp2f(dtv * a2[s]) * h[s] + du * sRow[ro + 24 + s];
  }
  size_t sb = ((size_t)blk*256 + t)*16;
  #pragma unroll
  for (int s = 0; s < DSt; ++s) SB_S[sb + s] = h[s];
  SB_dt[(size_t)blk*256 + t] = sumdt;
}

// Phase B (combine fused): prefix h_in over earlier chunks, re-run chunk,
// write UNGATED y to ydst (stride ys).
__global__ __launch_bounds__(256) void scanB_kernel(float* __restrict__ ydst_base, int ys,
                                                    const float* __restrict__ usrc, int uld,
                                                    const float* __restrict__ xdb,
                                                    const float* __restrict__ dpw,
                                                    const float* __restrict__ dpb,
                                                    const float* __restrict__ A_log,
                                                    const float* __restrict__ Dp,
                                                    const float* __restrict__ SB_S,
                                                    const float* __restrict__ SB_dt){
  __shared__ float sRow[CHS*56];
  __shared__ float sU[CHS*256];
  int blk = blockIdx.x;
  int c = blk % NCH; int bd = blk / NCH; int dch = bd % 3; int b = bd / 3;
  int t = threadIdx.x; int d = dch*256 + t;
  int l0 = c*CHS;
  for (int i = t; i < CHS*56; i += 256) sRow[i] = xdb[((size_t)(b*Ln + l0))*56 + i];
  const float* up = usrc + ((size_t)(b*Ln + l0))*uld + dch*256;
  #pragma unroll
  for (int i = 0; i < CHS; ++i) sU[i*256 + t] = up[(size_t)i*uld + t];
  float w[DTR];
  const float* wp = dpw + (size_t)d*DTR;
  #pragma unroll
  for (int j = 0; j < DTR; ++j) w[j] = wp[j];
  float a2[DSt], h[DSt];
  const float* ap = A_log + (size_t)d*DSt;
  #pragma unroll
  for (int s = 0; s < DSt; ++s){ a2[s] = -__expf(ap[s]) * LOG2E; h[s] = 0.f; }
  for (int cc = 0; cc < c; ++cc){
    size_t base = (((size_t)bd*NCH + cc)*256 + t)*16;
    float sd = SB_dt[((size_t)bd*NCH + cc)*256 + t];
    #pragma unroll
    for (int s = 0; s < DSt; ++s)
      h[s] = exp2f(sd * a2[s]) * h[s] + SB_S[base + s];
  }
  float dbias = dpb[d];
  float Dd = Dp[d];
  float* ydst = ydst_base + ((size_t)(b*Ln + l0))*ys + dch*256;
  __syncthreads();
  for (int i = 0; i < CHS; ++i){
    int ro = i*56;
    float dtr = dbias;
    #pragma unroll
    for (int j = 0; j < DTR; ++j) dtr += w[j] * sRow[ro + j];
    float dtv = fsoftplus(dtr);
    float u = sU[i*256 + t];
    float du = dtv * u;
    float yv = 0.f;
    #pragma unroll
    for (int s = 0; s < DSt; ++s){
      h[s] = exp2f(dtv * a2[s]) * h[s] + du * sRow[ro + 24 + s];
      yv += h[s] * sRow[ro + 40 + s];
    }
    ydst[(size_t)i*ys + t] = yv + u*Dd;
  }
}

// -------------------------------------------------- final two LayerNorms
__global__ __launch_bounds__(256) void final_ln_kernel(const float* __restrict__ h,
                                                       const float* __restrict__ res,
                                                       const float* w1, const float* b1,
                                                       const float* w2, const float* b2,
                                                       float* __restrict__ x){
  int wv = threadIdx.x >> 6, ln = threadIdx.x & 63;
  int tokid = blockIdx.x*4 + wv;
  const float* hr = h + (size_t)tokid*DM;
  const float* rr = res + (size_t)tokid*DM;
  float* xr = x + (size_t)tokid*DM;
  float v[6]; float s = 0.f;
  #pragma unroll
  for (int i = 0; i < 6; ++i){ int c = ln + 64*i; v[i] = hr[c] + rr[c]; s += v[i]; }
  #pragma unroll
  for (int o = 32; o > 0; o >>= 1) s += __shfl_xor(s, o);
  float mu = s * (1.f/DM); float q = 0.f;
  #pragma unroll
  for (int i = 0; i < 6; ++i){ float dd = v[i]-mu; q += dd*dd; }
  #pragma unroll
  for (int o = 32; o > 0; o >>= 1) q += __shfl_xor(q, o);
  float rstd = rsqrtf(q * (1.f/DM) + EPSf);
  float u[6]; float s2 = 0.f;
  #pragma unroll
  for (int i = 0; i < 6; ++i){ int c = ln + 64*i; u[i] = (v[i]-mu)*rstd*w1[c] + b1[c]; s2 += u[i]; }
  #pragma unroll
  for (int o = 32; o > 0; o >>= 1) s2 += __shfl_xor(s2, o);
  float mu2 = s2 * (1.f/DM); float q2 = 0.f;
  #pragma unroll
  for (int i = 0; i < 6; ++i){ float dd = u[i]-mu2; q2 += dd*dd; }
  #pragma unroll
  for (int o = 32; o > 0; o >>= 1) q2 += __shfl_xor(q2, o);
  float rstd2 = rsqrtf(q2 * (1.f/DM) + EPSf);
  #pragma unroll
  for (int i = 0; i < 6; ++i){ int c = ln + 64*i; xr[c] = (u[i]-mu2)*rstd2*w2[c] + b2[c]; }
}

// -------------------------------------------------- mean over L + MLP head
__global__ __launch_bounds__(384) void head_kernel(const float* __restrict__ x,
    const float* w1, const float* b1, const float* g1, const float* bb1,
    const float* w2, const float* b2, const float* g2, const float* bb2,
    const float* w3, const float* b3, float* __restrict__ out){
  int b = blockIdx.x; int t = threadIdx.x;
  __shared__ float feat[DM]; __shared__ float h1[256]; __shared__ float h2[256];
  float s = 0.f;
  for (int l = 0; l < Ln; ++l) s += x[((size_t)(b*Ln + l))*DM + t];
  feat[t] = s * (1.f/Ln);
  __syncthreads();
  if (t < 256){
    float a = b1[t];
    for (int j = 0; j < DM; ++j) a += w1[(size_t)t*DM + j] * feat[j];
    a = a * (g1[t] * BNS) + bb1[t];
    h1[t] = fmaxf(a, 0.f);
  }
  __syncthreads();
  if (t < 256){
    float a = b2[t];
    for (int j = 0; j < 256; ++j) a += w2[(size_t)t*256 + j] * h1[j];
    a = a * (g2[t] * BNS) + bb2[t];
    h2[t] = fmaxf(a, 0.f);
  }
  __syncthreads();
  if (t < CLSn){
    float a = b3[t];
    for (int j = 0; j < 256; ++j) a += w3[(size_t)t*256 + j] * h2[j];
    out[b*CLSn + t] = a;
  }
}

extern "C" void kernel_launch(void* const* d_in, const int* in_sizes, int n_in,
                              void* d_out, int out_size, void* d_ws, size_t ws_size,
                              hipStream_t stream) {
  if (n_in < 42) return;
  if (out_size < Bn*CLSn) return;
  constexpr size_t WS_FLOATS = 3919936;
  if (ws_size < WS_FLOATS * sizeof(float)) return;
  constexpr size_t MIDF = 5812224;          // bf16 weight cache (floats)
  constexpr size_t BIGF = 18874368;         // encoder F3in/F3/F1 (reused for ucv/SBS/SBdt)
  const bool mid = ws_size >= (WS_FLOATS + MIDF) * sizeof(float);
  const bool big = ws_size >= (WS_FLOATS + MIDF + BIGF) * sizeof(float);

  const float* pts       = (const float*)d_in[0];
  const float* enc_w1    = (const float*)d_in[1];  const float* enc_b1    = (const float*)d_in[2];
  const float* enc_bn1_g = (const float*)d_in[3];  const float* enc_bn1_b = (const float*)d_in[4];
  const float* enc_w2    = (const float*)d_in[5];  const float* enc_b2    = (const float*)d_in[6];
  const float* enc_w3    = (const float*)d_in[7];  const float* enc_b3    = (const float*)d_in[8];
  const float* enc_bn2_g = (const float*)d_in[9];  const float* enc_bn2_b = (const float*)d_in[10];
  const float* enc_w4    = (const float*)d_in[11]; const float* enc_b4    = (const float*)d_in[12];
  const float* pos_w1    = (const float*)d_in[13]; const float* pos_b1    = (const float*)d_in[14];
  const float* pos_w2    = (const float*)d_in[15]; const float* pos_b2    = (const float*)d_in[16];
  const float* ln_w      = (const float*)d_in[17]; const float* ln_b      = (const float*)d_in[18];
  const float* in_proj_w = (const float*)d_in[19];
  const float* conv_w    = (const float*)d_in[20]; const float* conv_b    = (const float*)d_in[21];
  const float* x_proj_w  = (const float*)d_in[22];
  const float* dt_proj_w = (const float*)d_in[23]; const float* dt_proj_b = (const float*)d_in[24];
  const float* A_log     = (const float*)d_in[25]; const float* D_param   = (const float*)d_in[26];
  const float* out_proj_w= (const float*)d_in[27];
  const float* normf_w   = (const float*)d_in[28]; const float* normf_b   = (const float*)d_in[29];
  const float* norm_w    = (const float*)d_in[30]; const float* norm_b    = (const float*)d_in[31];
  const float* head_w1   = (const float*)d_in[32]; const float* head_b1   = (const float*)d_in[33];
  const float* head_bn1_g= (const float*)d_in[34]; const float* head_bn1_b= (const float*)d_in[35];
  const float* head_w2   = (const float*)d_in[36]; const float* head_b2   = (const float*)d_in[37];
  const float* head_bn2_g= (const float*)d_in[38]; const float* head_bn2_b= (const float*)d_in[39];
  const float* head_w3   = (const float*)d_in[40]; const float* head_b3   = (const float*)d_in[41];

  float* ws = (float*)d_ws;
  float* hb   = ws;                   // 589,824 floats
  float* resb = ws + 589824;          // 589,824
  float* U    = ws + 1179648;         // 2,740,224
  // setup/encoder view of U
  float* center = U;
  float* nb     = U + 1536;
  float* tok    = U + 50688;
  int*   order  = (int*)(U + 247296);
  float* eb0    = U + 262144;
  float* eb1    = U + 1310720;
  // mamba view of U
  float* xz   = U;                      // 2,359,296 (1536 x 1536)
  float* xdb  = U + 2359296;            // 86,016
  bf16*  xb   = (bf16*)(U + 2445312);   // 589,824 bf16
  float* SBdt_s = U + 2445312;          // small path (xb dead when scanA runs)
  float* BND  = U + 2482176;            // small path
  float* SBS_s  = hb;                   // small path (hb dead between ln_res and out_proj)
  float* xf   = U;
  // mid tier: bf16 weight cache
  float* WB = ws + WS_FLOATS;
  bf16* wb_ip = (bf16*)WB;                  // 12x1536x384
  bf16* wb_op = (bf16*)(WB + 3538944);      // 12x384x768
  bf16* wb_xp = (bf16*)(WB + 5308416);      // 12x56x768
  bf16* wb_e2 = (bf16*)(WB + 5566464);      // 256x128
  bf16* wb_e3 = (bf16*)(WB + 5582848);      // 512x512
  bf16* wb_e4 = (bf16*)(WB + 5713920);      // 384x512
  // big tier buffers (encoder first, then reused in mamba loop)
  float* F3in = WB + MIDF;                  // 8,388,608 (16384 x 512)
  float* F3   = WB + MIDF + 8388608;        // 8,388,608
  float* F1   = WB + MIDF + 16777216;       // 2,097,152
  float* F4   = F3in;
  float* ucv  = F3in;                       // y/u buffer (1536x768) after encoder
  float* SBS_b  = F3;                       // 144*256*16 = 589,824 fits
  float* SBdt_b = F1;                       // 36,864 fits

  if (mid)
    cvt_all<<<11352, 256, 0, stream>>>(in_proj_w, out_proj_w, x_proj_w,
                                       enc_w2, enc_w3, enc_w4, (bf16*)WB);

  fps_kernel<<<Bn, 64, 0, stream>>>(pts, center);
  knn_kernel<<<Bn*Gn, 256, 0, stream>>>(pts, center, nb);

  if (big){
    gemm_mfma<float,float,1,0><<<dim3(256,2), 256, 0, stream>>>(nb, 3, enc_w1, enc_b1,
        enc_bn1_g, enc_bn1_b, F1, 128, 16384, 128, 3);
    gemm_mfma<float,bf16,0,0><<<dim3(256,4), 256, 0, stream>>>(F1, 128, wb_e2, enc_b2,
        nullptr, nullptr, F3in + 256, 512, 16384, 256, 128);
    maxk_fg<<<512, 256, 0, stream>>>(F3in);
    gemm_mfma<float,bf16,1,0><<<dim3(256,8), 256, 0, stream>>>(F3in, 512, wb_e3, enc_b3,
        enc_bn2_g, enc_bn2_b, F3, 512, 16384, 512, 512);
    gemm_mfma<float,bf16,0,0><<<dim3(256,6), 256, 0, stream>>>(F3, 512, wb_e4, enc_b4,
        nullptr, nullptr, F4, 384, 16384, 384, 512);
    maxk_tok<<<512, 384, 0, stream>>>(F4, tok);
  } else {
    for (int ch = 0; ch < 8; ++ch){
      const float* nb_c = nb + (size_t)ch*2048*3;
      float* tok_c = tok + (size_t)ch*64*DM;
      gemm_mfma<float,float,1,0><<<dim3(32,2), 256, 0, stream>>>(nb_c, 3, enc_w1, enc_b1,
          enc_bn1_g, enc_bn1_b, eb1, 128, 2048, 128, 3);
      if (mid){
        gemm_mfma<float,bf16,0,0><<<dim3(32,4), 256, 0, stream>>>(eb1, 128, wb_e2, enc_b2,
            nullptr, nullptr, eb0 + 256, 512, 2048, 256, 128);
        maxk_fg<<<64, 256, 0, stream>>>(eb0);
        gemm_mfma<float,bf16,1,0><<<dim3(32,8), 256, 0, stream>>>(eb0, 512, wb_e3, enc_b3,
            enc_bn2_g, enc_bn2_b, eb1, 512, 2048, 512, 512);
        gemm_mfma<float,bf16,0,0><<<dim3(32,6), 256, 0, stream>>>(eb1, 512, wb_e4, enc_b4,
            nullptr, nullptr, eb0, 384, 2048, 384, 512);
      } else {
        gemm_mfma<float,float,0,0><<<dim3(32,4), 256, 0, stream>>>(eb1, 128, enc_w2, enc_b2,
            nullptr, nullptr, eb0 + 256, 512, 2048, 256, 128);
        maxk_fg<<<64, 256, 0, stream>>>(eb0);
        gemm_mfma<float,float,1,0><<<dim3(32,8), 256, 0, stream>>>(eb0, 512, enc_w3, enc_b3,
            enc_bn2_g, enc_bn2_b, eb1, 512, 2048, 512, 512);
        gemm_mfma<float,float,0,0><<<dim3(32,6), 256, 0, stream>>>(eb1, 512, enc_w4, enc_b4,
            nullptr, nullptr, eb0, 384, 2048, 384, 512);
      }
      maxk_tok<<<64, 384, 0, stream>>>(eb0, tok_c);
    }
  }

  pos_kernel<<<Bn*Gn, 128, 0, stream>>>(center, pos_w1, pos_b1, pos_w2, pos_b2, tok);
  sort_kernel<<<Bn*3, 128, 0, stream>>>(center, order);
  build_h<<<(Bn*Ln*DM + 255)/256, 256, 0, stream>>>(tok, order, hb, resb);

  for (int l = 0; l < DEPTH; ++l){
    const float* lnw  = ln_w      + (size_t)l*DM;
    const float* lnb  = ln_b      + (size_t)l*DM;
    const float* ipw  = in_proj_w + (size_t)l*1536*DM;
    const float* cw   = conv_w    + (size_t)l*DI*4;
    const float* cb   = conv_b    + (size_t)l*DI;
    const float* xpw  = x_proj_w  + (size_t)l*56*DI;
    const float* dpw  = dt_proj_w + (size_t)l*DI*DTR;
    const float* dpb  = dt_proj_b + (size_t)l*DI;
    const float* Alg  = A_log     + (size_t)l*DI*DSt;
    const float* Dpar = D_param   + (size_t)l*DI;
    const float* opw  = out_proj_w+ (size_t)l*DM*DI;

    ln_res_kernel<<<Bn*Ln/4, 256, 0, stream>>>(hb, resb, xb, lnw, lnb);
    if (mid){
      gemm_mfma<bf16,bf16,0,0><<<dim3(24,24), 256, 0, stream>>>(xb, DM,
          wb_ip + (size_t)l*1536*DM, nullptr, nullptr, nullptr, xz, 1536, Bn*Ln, 1536, DM);
    } else {
      gemm_mfma<bf16,float,0,0><<<dim3(24,24), 256, 0, stream>>>(xb, DM, ipw,
          nullptr, nullptr, nullptr, xz, 1536, Bn*Ln, 1536, DM);
    }
    if (big){
      conv_fused<<<Bn*3*NLC, 256, 0, stream>>>(xz, ucv, cw, cb);
      if (mid)
        gemm_mfma<float,bf16,0,0><<<dim3(24,1), 256, 0, stream>>>(ucv, DI,
            wb_xp + (size_t)l*56*DI, nullptr, nullptr, nullptr, xdb, 56, Bn*Ln, 56, DI);
      else
        gemm_mfma<float,float,0,0><<<dim3(24,1), 256, 0, stream>>>(ucv, DI, xpw,
            nullptr, nullptr, nullptr, xdb, 56, Bn*Ln, 56, DI);
      scanA_kernel<<<Bn*3*NCH, 256, 0, stream>>>(ucv, DI, xdb, dpw, dpb, Alg, SBS_b, SBdt_b);
      scanB_kernel<<<Bn*3*NCH, 256, 0, stream>>>(xz, 1536, ucv, DI,
          xdb, dpw, dpb, Alg, Dpar, SBS_b, SBdt_b);
    } else {
      conv_save<<<Bn*3*NLC, 256, 0, stream>>>(xz, BND);
      conv_apply<<<Bn*3*NLC, 256, 0, stream>>>(xz, BND, cw, cb);
      if (mid)
        gemm_mfma<float,bf16,0,0><<<dim3(24,1), 256, 0, stream>>>(xz, 1536,
            wb_xp + (size_t)l*56*DI, nullptr, nullptr, nullptr, xdb, 56, Bn*Ln, 56, DI);
      else
        gemm_mfma<float,float,0,0><<<dim3(24,1), 256, 0, stream>>>(xz, 1536, xpw,
            nullptr, nullptr, nullptr, xdb, 56, Bn*Ln, 56, DI);
      scanA_kernel<<<Bn*3*NCH, 256, 0, stream>>>(xz, 1536, xdb, dpw, dpb, Alg, SBS_s, SBdt_s);
      scanB_kernel<<<Bn*3*NCH, 256, 0, stream>>>(xz, 1536, xz, 1536,
          xdb, dpw, dpb, Alg, Dpar, SBS_s, SBdt_s);
    }
    if (mid){
      gemm_mfma<float,bf16,0,1><<<dim3(24,6), 256, 0, stream>>>(xz, 1536,
          wb_op + (size_t)l*DM*DI, nullptr, xz, nullptr, hb, DM, Bn*Ln, DM, DI);
    } else {
      gemm_mfma<float,float,0,1><<<dim3(24,6), 256, 0, stream>>>(xz, 1536, opw,
          nullptr, xz, nullptr, hb, DM, Bn*Ln, DM, DI);
    }
  }

  final_ln_kernel<<<Bn*Ln/4, 256, 0, stream>>>(hb, resb, normf_w, normf_b, norm_w, norm_b, xf);
  head_kernel<<<Bn, 384, 0, stream>>>(xf, head_w1, head_b1, head_bn1_g, head_bn1_b,
                                      head_w2, head_b2, head_bn2_g, head_bn2_b,
                                      head_w3, head_b3, (float*)d_out);
}

// Round 15
// 1606.879 us; speedup vs baseline: 1.2973x; 1.0948x over previous
//
#include <hip/hip_runtime.h>
#include <hip/hip_bf16.h>

using bf16 = __hip_bfloat16;
using short8  = __attribute__((ext_vector_type(8))) short;
using floatx4 = __attribute__((ext_vector_type(4))) float;
using ull = unsigned long long;

constexpr int Bn = 4, Np = 1024, Gn = 128, Kn = 32;
constexpr int DM = 384, DEPTH = 12, CLSn = 40;
constexpr int DI = 768, DSt = 16, DTR = 24;
constexpr int Ln = 384;
constexpr int NCH = 12, CHS = 32;      // scan: 12 chunks x 32 steps
constexpr int NLC = 24;                // conv: 24 chunks x 16 steps
constexpr float EPSf = 1e-5f;
constexpr float BNS = 0.99999500003749968752f; // 1/sqrt(1+1e-5)
constexpr float LOG2E = 1.4426950408889634f;

static __device__ __forceinline__ short f2bf(float f){
  bf16 h = __float2bfloat16(f);
  return *reinterpret_cast<short*>(&h);
}
static __device__ __forceinline__ float fsig(float x){ return 1.f/(1.f + __expf(-x)); }
static __device__ __forceinline__ float fsoftplus(float x){
  return fmaxf(x, 0.f) + __logf(1.f + __expf(-fabsf(x)));
}

template<int CTRL>
static __device__ __forceinline__ int dppmov(int x){
  return __builtin_amdgcn_update_dpp(0, x, CTRL, 0xF, 0xF, true);
}
static __device__ __forceinline__ ull redmax64(ull key){
  #define RSTEP(CTRL) { \
    int hi = (int)(unsigned)(key >> 32), lo = (int)(unsigned)key; \
    int h2 = dppmov<CTRL>(hi), l2 = dppmov<CTRL>(lo); \
    ull k2 = ((ull)(unsigned)h2 << 32) | (unsigned)l2; \
    if (k2 > key) key = k2; }
  RSTEP(0x111) RSTEP(0x112) RSTEP(0x114) RSTEP(0x118) RSTEP(0x142) RSTEP(0x143)
  #undef RSTEP
  return key;
}

// ---------------------------------------------------------------- FPS
__global__ __launch_bounds__(64) void fps_kernel(const float* __restrict__ pts,
                                                 float* __restrict__ center){
  int b = blockIdx.x, t = threadIdx.x;
  __shared__ float xs[1024], ys[1024], zs[1024];
  const float* p = pts + (size_t)b * Np * 3;
  float X[16], Y[16], Z[16], D[16];
  #pragma unroll
  for (int i = 0; i < 16; ++i){
    int n = t + 64*i;
    float a = p[n*3+0], c = p[n*3+1], e = p[n*3+2];
    X[i] = a; Y[i] = c; Z[i] = e;
    xs[n] = a; ys[n] = c; zs[n] = e;
    D[i] = 1e10f;
  }
  __syncthreads();
  float px = xs[0], py = ys[0], pz = zs[0];
  if (t == 0){
    center[(size_t)(b*Gn)*3+0] = px;
    center[(size_t)(b*Gn)*3+1] = py;
    center[(size_t)(b*Gn)*3+2] = pz;
  }
  for (int it = 1; it < Gn; ++it){
    float v = -1.f; int nbest = t;
    #pragma unroll
    for (int i = 0; i < 16; ++i){
      float dx = __fsub_rn(X[i], px);
      float dy = __fsub_rn(Y[i], py);
      float dz = __fsub_rn(Z[i], pz);
      float d  = __fadd_rn(__fadd_rn(__fmul_rn(dx,dx), __fmul_rn(dy,dy)), __fmul_rn(dz,dz));
      float dm = fminf(D[i], d); D[i] = dm;
      if (dm > v){ v = dm; nbest = t + 64*i; }
    }
    ull key = ((ull)__float_as_uint(v) << 32) | (unsigned)(Np-1 - nbest);
    key = redmax64(key);
    int lo63 = __builtin_amdgcn_readlane((int)(unsigned)(key & 0xFFFFFFFFu), 63);
    int wn = Np-1 - lo63;
    wn = min(max(wn, 0), Np-1);
    px = xs[wn]; py = ys[wn]; pz = zs[wn];
    if (t == 0){
      center[(size_t)(b*Gn+it)*3+0] = px;
      center[(size_t)(b*Gn+it)*3+1] = py;
      center[(size_t)(b*Gn+it)*3+2] = pz;
    }
  }
}

// ---------------------------------------------------------------- KNN
__global__ __launch_bounds__(256) void knn_kernel(const float* __restrict__ pts,
                                                  const float* __restrict__ center,
                                                  float* __restrict__ nb){
  int gid = blockIdx.x; int b = gid >> 7;
  __shared__ float d2[1024];
  __shared__ float rv[4]; __shared__ int ri[4];
  int t = threadIdx.x;
  float cx = center[(size_t)gid*3+0], cy = center[(size_t)gid*3+1], cz = center[(size_t)gid*3+2];
  const float* p = pts + (size_t)b * Np * 3;
  for (int n = t; n < Np; n += 256){
    float dx = __fsub_rn(cx, p[n*3+0]);
    float dy = __fsub_rn(cy, p[n*3+1]);
    float dz = __fsub_rn(cz, p[n*3+2]);
    d2[n] = __fadd_rn(__fadd_rn(__fmul_rn(dx,dx), __fmul_rn(dy,dy)), __fmul_rn(dz,dz));
  }
  __syncthreads();
  for (int kk = 0; kk < Kn; ++kk){
    float v = 3e38f; int idx = 0;
    for (int n = t; n < Np; n += 256){
      float d = d2[n];
      if (d < v || (d == v && n < idx)){ v = d; idx = n; }
    }
    ull key = ((ull)(unsigned)(~__float_as_uint(v)) << 32) | (unsigned)(Np-1 - idx);
    key = redmax64(key);
    if ((t & 63) == 63){
      rv[t>>6] = __uint_as_float(~(unsigned)(key >> 32));
      ri[t>>6] = Np-1 - (int)(unsigned)(key & 0xFFFFFFFFu);
    }
    __syncthreads();
    if (t == 0){
      float bv = rv[0]; int bi = ri[0];
      for (int w = 1; w < 4; ++w){
        if (rv[w] < bv || (rv[w] == bv && ri[w] < bi)){ bv = rv[w]; bi = ri[w]; }
      }
      bi = min(max(bi, 0), Np-1);
      nb[((size_t)gid*Kn+kk)*3+0] = __fsub_rn(p[bi*3+0], cx);
      nb[((size_t)gid*Kn+kk)*3+1] = __fsub_rn(p[bi*3+1], cy);
      nb[((size_t)gid*Kn+kk)*3+2] = __fsub_rn(p[bi*3+2], cz);
      d2[bi] = 3e38f;
    }
    __syncthreads();
  }
}

// ---------------------------------------------------------------- all weight conversions, one dispatch
__global__ __launch_bounds__(256) void cvt_all(const float* __restrict__ s0,
    const float* __restrict__ s1, const float* __restrict__ s2,
    const float* __restrict__ s3, const float* __restrict__ s4,
    const float* __restrict__ s5, bf16* __restrict__ dst){
  long i = ((long)blockIdx.x*256 + threadIdx.x)*4;
  if (i >= 11624448L) return;
  const float* s; long off;
  if      (i <  7077888L){ s = s0; off = 0L; }
  else if (i < 10616832L){ s = s1; off =  7077888L; }
  else if (i < 11132928L){ s = s2; off = 10616832L; }
  else if (i < 11165696L){ s = s3; off = 11132928L; }
  else if (i < 11427840L){ s = s4; off = 11165696L; }
  else                   { s = s5; off = 11427840L; }
  float4 v = *(const float4*)(s + (i - off));
  short* o = (short*)dst + i;
  o[0] = f2bf(v.x); o[1] = f2bf(v.y); o[2] = f2bf(v.z); o[3] = f2bf(v.w);
}

// ---------------------------------------------------------------- MFMA GEMM 64x64, BK=32 (guarded; for K=3)
template<typename AT, typename WT, int ACT, int MODE>
__global__ __launch_bounds__(256) void gemm_mfma(const AT* __restrict__ A, int lda,
                                                 const WT* __restrict__ W,
                                                 const float* __restrict__ bias,
                                                 const float* __restrict__ gz,
                                                 const float* __restrict__ bbp,
                                                 float* __restrict__ C, int ldc,
                                                 int M, int N, int K){
  __shared__ __align__(16) short As[64*40];
  __shared__ __align__(16) short Ws[64*40];
  int bm = blockIdx.x * 64, bn = blockIdx.y * 64;
  int t = threadIdx.x;
  int row = t >> 2;
  int kseg = (t & 3) * 8;
  int w = t >> 6, lane = t & 63, m16 = lane & 15, q = lane >> 4;
  floatx4 acc[4] = {};
  for (int k0 = 0; k0 < K; k0 += 32){
    {
      const float* Ar = (const float*)A + (size_t)(bm + row)*lda;
      short* dst = &As[row*40 + kseg];
      #pragma unroll
      for (int j = 0; j < 8; ++j){
        int k = k0 + kseg + j;
        dst[j] = (k < K) ? f2bf(Ar[k]) : (short)0;
      }
    }
    {
      int n = bn + row;
      short* dst = &Ws[row*40 + kseg];
      #pragma unroll
      for (int j = 0; j < 8; ++j){
        int k = k0 + kseg + j;
        dst[j] = (n < N && k < K) ? f2bf(((const float*)W)[(size_t)n*K + k]) : (short)0;
      }
    }
    __syncthreads();
    short8 af = *(const short8*)&As[(w*16 + m16)*40 + q*8];
    #pragma unroll
    for (int j = 0; j < 4; ++j){
      short8 bfr = *(const short8*)&Ws[(j*16 + m16)*40 + q*8];
      acc[j] = __builtin_amdgcn_mfma_f32_16x16x32_bf16(af, bfr, acc[j], 0, 0, 0);
    }
    __syncthreads();
  }
  #pragma unroll
  for (int j = 0; j < 4; ++j){
    int n = bn + j*16 + m16;
    if (n < N){
      float bv = bias ? bias[n] : 0.f;
      float gv = 0.f, bbv = 0.f;
      if (ACT == 1){ gv = gz[n] * BNS; bbv = bbp[n]; }
      #pragma unroll
      for (int r = 0; r < 4; ++r){
        int m = bm + w*16 + q*4 + r;
        float v = acc[j][r] + bv;
        if (ACT == 1){ v = v * gv + bbv; v = fmaxf(v, 0.f); }
        C[(size_t)m*ldc + n] = v;
      }
    }
  }
}

// ---------------------------------------------------------------- MFMA GEMM 64x64, BK=64
// Requires K%64==0, M%64==0. MODE 0: plain A. MODE 1 (GATE): A=y(lda),
// z at gz + m*1536 + 768 + k; element = y*silu(z). N guarded (x_proj N=56).
template<typename AT, typename WT, int ACT, int MODE>
__global__ __launch_bounds__(256) void gemm_mfma64(const AT* __restrict__ A, int lda,
                                                   const WT* __restrict__ W,
                                                   const float* __restrict__ bias,
                                                   const float* __restrict__ gz,
                                                   const float* __restrict__ bbp,
                                                   float* __restrict__ C, int ldc,
                                                   int M, int N, int K){
  __shared__ __align__(16) short As[64*72];
  __shared__ __align__(16) short Ws[64*72];
  int bm = blockIdx.x * 64, bn = blockIdx.y * 64;
  int t = threadIdx.x;
  int row = t >> 2;            // 0..63
  int kseg = (t & 3) * 16;     // 0,16,32,48
  int w = t >> 6, lane = t & 63, m16 = lane & 15, q = lane >> 4;
  floatx4 acc[4] = {};
  for (int k0 = 0; k0 < K; k0 += 64){
    // ---- A staging (16 elements/thread)
    if constexpr (MODE == 1){
      const float* Yr = (const float*)A + (size_t)(bm + row)*lda + k0 + kseg;
      const float* Zr = gz + (size_t)(bm + row)*1536 + 768 + k0 + kseg;
      float y[16], z[16];
      #pragma unroll
      for (int j = 0; j < 4; ++j){
        *(float4*)&y[j*4] = *(const float4*)(Yr + j*4);
        *(float4*)&z[j*4] = *(const float4*)(Zr + j*4);
      }
      short* dst = &As[row*72 + kseg];
      #pragma unroll
      for (int jj = 0; jj < 16; ++jj) dst[jj] = f2bf(y[jj] * (z[jj] * fsig(z[jj])));
    } else if constexpr (sizeof(AT) == 2){
      const short* Ar = (const short*)A + (size_t)(bm + row)*lda + k0 + kseg;
      *(short8*)&As[row*72 + kseg]     = *(const short8*)Ar;
      *(short8*)&As[row*72 + kseg + 8] = *(const short8*)(Ar + 8);
    } else {
      const float* Ar = (const float*)A + (size_t)(bm + row)*lda + k0 + kseg;
      float a[16];
      #pragma unroll
      for (int j = 0; j < 4; ++j) *(float4*)&a[j*4] = *(const float4*)(Ar + j*4);
      short* dst = &As[row*72 + kseg];
      #pragma unroll
      for (int jj = 0; jj < 16; ++jj) dst[jj] = f2bf(a[jj]);
    }
    // ---- W staging
    {
      int n = bn + row;
      if constexpr (sizeof(WT) == 2){
        short8 v0, v1;
        #pragma unroll
        for (int j = 0; j < 8; ++j){ v0[j] = 0; v1[j] = 0; }
        if (n < N){
          const short* Wr = (const short*)W + (size_t)n*K + k0 + kseg;
          v0 = *(const short8*)Wr;
          v1 = *(const short8*)(Wr + 8);
        }
        *(short8*)&Ws[row*72 + kseg]     = v0;
        *(short8*)&Ws[row*72 + kseg + 8] = v1;
      } else {
        short* dst = &Ws[row*72 + kseg];
        if (n < N){
          const float* Wr = (const float*)W + (size_t)n*K + k0 + kseg;
          float wv[16];
          #pragma unroll
          for (int j = 0; j < 4; ++j) *(float4*)&wv[j*4] = *(const float4*)(Wr + j*4);
          #pragma unroll
          for (int jj = 0; jj < 16; ++jj) dst[jj] = f2bf(wv[jj]);
        } else {
          #pragma unroll
          for (int jj = 0; jj < 16; ++jj) dst[jj] = 0;
        }
      }
    }
    __syncthreads();
    short8 af0 = *(const short8*)&As[(w*16 + m16)*72 + q*8];
    short8 af1 = *(const short8*)&As[(w*16 + m16)*72 + 32 + q*8];
    #pragma unroll
    for (int j = 0; j < 4; ++j){
      short8 b0 = *(const short8*)&Ws[(j*16 + m16)*72 + q*8];
      acc[j] = __builtin_amdgcn_mfma_f32_16x16x32_bf16(af0, b0, acc[j], 0, 0, 0);
      short8 b1 = *(const short8*)&Ws[(j*16 + m16)*72 + 32 + q*8];
      acc[j] = __builtin_amdgcn_mfma_f32_16x16x32_bf16(af1, b1, acc[j], 0, 0, 0);
    }
    __syncthreads();
  }
  #pragma unroll
  for (int j = 0; j < 4; ++j){
    int n = bn + j*16 + m16;
    if (n < N){
      float bv = bias ? bias[n] : 0.f;
      float gv = 0.f, bbv = 0.f;
      if (ACT == 1){ gv = gz[n] * BNS; bbv = bbp[n]; }
      #pragma unroll
      for (int r = 0; r < 4; ++r){
        int m = bm + w*16 + q*4 + r;
        float v = acc[j][r] + bv;
        if (ACT == 1){ v = v * gv + bbv; v = fmaxf(v, 0.f); }
        C[(size_t)m*ldc + n] = v;
      }
    }
  }
}

// -------------------------------------------------- encoder max-pools
__global__ __launch_bounds__(256) void maxk_fg(float* __restrict__ f3in){
  int gg = blockIdx.x; int c = threadIdx.x;
  float m = -3e38f;
  for (int k = 0; k < Kn; ++k) m = fmaxf(m, f3in[((size_t)gg*Kn + k)*512 + 256 + c]);
  for (int k = 0; k < Kn; ++k) f3in[((size_t)gg*Kn + k)*512 + c] = m;
}

__global__ __launch_bounds__(384) void maxk_tok(const float* __restrict__ f4, float* __restrict__ tok){
  int gg = blockIdx.x; int c = threadIdx.x;
  float m = -3e38f;
  for (int k = 0; k < Kn; ++k) m = fmaxf(m, f4[((size_t)gg*Kn + k)*DM + c]);
  tok[(size_t)gg*DM + c] = m;
}

// -------------------------------------------------- pos embedding (adds into tok)
__global__ __launch_bounds__(128) void pos_kernel(const float* __restrict__ center,
                                                  const float* __restrict__ w1, const float* __restrict__ b1,
                                                  const float* __restrict__ w2, const float* __restrict__ b2,
                                                  float* __restrict__ tok){
  int gid = blockIdx.x;
  __shared__ float h1[128]; __shared__ float c3[3];
  int t = threadIdx.x;
  if (t < 3) c3[t] = center[(size_t)gid*3 + t];
  __syncthreads();
  float a = w1[t*3+0]*c3[0] + w1[t*3+1]*c3[1] + w1[t*3+2]*c3[2] + b1[t];
  h1[t] = 0.5f * a * (1.f + erff(a * 0.70710678118654752440f));
  __syncthreads();
  for (int c = t; c < DM; c += 128){
    float s = b2[c];
    for (int j = 0; j < 128; ++j) s += w2[(size_t)c*128 + j] * h1[j];
    tok[(size_t)gid*DM + c] += s;
  }
}

// -------------------------------------------------- stable argsort (rank count)
__global__ __launch_bounds__(128) void sort_kernel(const float* __restrict__ center,
                                                   int* __restrict__ order){
  int bax = blockIdx.x; int b = bax / 3, ax = bax % 3;
  __shared__ float key[128];
  int t = threadIdx.x;
  key[t] = center[(size_t)(b*Gn + t)*3 + ax];
  __syncthreads();
  float kt = key[t]; int r = 0;
  for (int j = 0; j < Gn; ++j){
    float kj = key[j];
    r += (kj < kt || (kj == kt && j < t)) ? 1 : 0;
  }
  r = min(max(r, 0), Gn-1);
  order[b*Ln + ax*Gn + r] = t;
}

// -------------------------------------------------- token gather + res init
__global__ __launch_bounds__(256) void build_h(const float* __restrict__ tok,
                        const int* __restrict__ order,
                        float* __restrict__ h, float* __restrict__ res){
  int i = blockIdx.x * blockDim.x + threadIdx.x;
  if (i >= Bn*Ln*DM) return;
  int c = i % DM; int l = (i / DM) % Ln; int b = i / (DM*Ln);
  int src = order[b*Ln + l];
  src = min(max(src, 0), Gn-1);
  h[i] = tok[((size_t)(b*Gn + src))*DM + c];
  res[i] = 0.f;
}

// -------------------------------------------------- res += h; x = LN(res)*w+b (bf16 out)
__global__ __launch_bounds__(256) void ln_res_kernel(const float* __restrict__ h,
                                                     float* __restrict__ res,
                                                     bf16* __restrict__ x,
                                                     const float* __restrict__ w,
                                                     const float* __restrict__ bias){
  int wv = threadIdx.x >> 6, ln = threadIdx.x & 63;
  int tokid = blockIdx.x*4 + wv;
  const float* hr = h + (size_t)tokid*DM;
  float* rr = res + (size_t)tokid*DM;
  bf16* xr = x + (size_t)tokid*DM;
  float v[6]; float s = 0.f;
  #pragma unroll
  for (int i = 0; i < 6; ++i){ int c = ln + 64*i; float t = hr[c] + rr[c]; rr[c] = t; v[i] = t; s += t; }
  #pragma unroll
  for (int o = 32; o > 0; o >>= 1) s += __shfl_xor(s, o);
  float mu = s * (1.f/DM);
  float q = 0.f;
  #pragma unroll
  for (int i = 0; i < 6; ++i){ float d = v[i] - mu; q += d*d; }
  #pragma unroll
  for (int o = 32; o > 0; o >>= 1) q += __shfl_xor(q, o);
  float rstd = rsqrtf(q * (1.f/DM) + EPSf);
  #pragma unroll
  for (int i = 0; i < 6; ++i){ int c = ln + 64*i;
    xr[c] = __float2bfloat16((v[i]-mu)*rstd*w[c] + bias[c]); }
}

// -------------------------------------------------- conv (big path): xz -> ucv
__global__ __launch_bounds__(256) void conv_fused(const float* __restrict__ xz,
                                                  float* __restrict__ ucv,
                                                  const float* __restrict__ cw,
                                                  const float* __restrict__ cb){
  int blk = blockIdx.x;
  int lc = blk % NLC; int bd = blk / NLC; int dch = bd % 3; int b = bd / 3;
  int t = threadIdx.x; int d = dch*256 + t;
  int l0 = lc*16;
  float w0 = cw[d*4+0], w1 = cw[d*4+1], w2 = cw[d*4+2], w3 = cw[d*4+3];
  float bias = cb[d];
  float u0 = (l0 >= 3) ? xz[((size_t)(b*Ln + l0-3))*1536 + d] : 0.f;
  float u1 = (l0 >= 2) ? xz[((size_t)(b*Ln + l0-2))*1536 + d] : 0.f;
  float u2 = (l0 >= 1) ? xz[((size_t)(b*Ln + l0-1))*1536 + d] : 0.f;
  const float* pin = xz + ((size_t)(b*Ln + l0))*1536 + d;
  float* pout = ucv + ((size_t)(b*Ln + l0))*DI + d;
  float r[16];
  #pragma unroll
  for (int i = 0; i < 16; ++i) r[i] = pin[(size_t)i*1536];
  #pragma unroll
  for (int i = 0; i < 16; ++i){
    float v = u0*w0 + u1*w1 + u2*w2 + r[i]*w3 + bias;
    pout[(size_t)i*DI] = v * fsig(v);
    u0 = u1; u1 = u2; u2 = r[i];
  }
}

// -------------------------------------------------- conv (small path): 2-pass in place
__global__ __launch_bounds__(256) void conv_save(const float* __restrict__ xz,
                                                 float* __restrict__ bnd){
  int blk = blockIdx.x;
  int lc = blk % NLC; int bd = blk / NLC; int dch = bd % 3; int b = bd / 3;
  int t = threadIdx.x; int d = dch*256 + t;
  int l0 = lc*16;
  #pragma unroll
  for (int j = 0; j < 3; ++j){
    int l = l0 - 3 + j;
    float v = (l >= 0) ? xz[((size_t)(b*Ln + l))*1536 + d] : 0.f;
    bnd[(((size_t)blk)*3 + j)*256 + t] = v;
  }
}

__global__ __launch_bounds__(256) void conv_apply(float* __restrict__ xz,
                                                  const float* __restrict__ bnd,
                                                  const float* __restrict__ cw,
                                                  const float* __restrict__ cb){
  int blk = blockIdx.x;
  int lc = blk % NLC; int bd = blk / NLC; int dch = bd % 3; int b = bd / 3;
  int t = threadIdx.x; int d = dch*256 + t;
  int l0 = lc*16;
  float w0 = cw[d*4+0], w1 = cw[d*4+1], w2 = cw[d*4+2], w3 = cw[d*4+3];
  float bias = cb[d];
  float u0 = bnd[(((size_t)blk)*3 + 0)*256 + t];
  float u1 = bnd[(((size_t)blk)*3 + 1)*256 + t];
  float u2 = bnd[(((size_t)blk)*3 + 2)*256 + t];
  float* p = xz + ((size_t)(b*Ln + l0))*1536 + d;
  float r[16];
  #pragma unroll
  for (int i = 0; i < 16; ++i) r[i] = p[(size_t)i*1536];
  #pragma unroll
  for (int i = 0; i < 16; ++i){
    float v = u0*w0 + u1*w1 + u2*w2 + r[i]*w3 + bias;
    p[(size_t)i*1536] = v * fsig(v);
    u0 = u1; u1 = u2; u2 = r[i];
  }
}

// -------------------------------------------------- chunked selective scan
__global__ __launch_bounds__(256) void scanA_kernel(const float* __restrict__ usrc, int uld,
                                                    const float* __restrict__ xdb,
                                                    const float* __restrict__ dpw,
                                                    const float* __restrict__ dpb,
                                                    const float* __restrict__ A_log,
                                                    float* __restrict__ SB_S,
                                                    float* __restrict__ SB_dt){
  __shared__ float sRow[CHS*56];
  __shared__ float sU[CHS*256];
  int blk = blockIdx.x;
  int c = blk % NCH; int bd = blk / NCH; int dch = bd % 3; int b = bd / 3;
  int t = threadIdx.x; int d = dch*256 + t;
  int l0 = c*CHS;
  for (int i = t; i < CHS*56; i += 256) sRow[i] = xdb[((size_t)(b*Ln + l0))*56 + i];
  const float* up = usrc + ((size_t)(b*Ln + l0))*uld + dch*256;
  #pragma unroll
  for (int i = 0; i < CHS; ++i) sU[i*256 + t] = up[(size_t)i*uld + t];
  float w[DTR];
  const float* wp = dpw + (size_t)d*DTR;
  #pragma unroll
  for (int j = 0; j < DTR; ++j) w[j] = wp[j];
  float a2[DSt], h[DSt];
  const float* ap = A_log + (size_t)d*DSt;
  #pragma unroll
  for (int s = 0; s < DSt; ++s){ a2[s] = -__expf(ap[s]) * LOG2E; h[s] = 0.f; }
  float dbias = dpb[d];
  float sumdt = 0.f;
  __syncthreads();
  for (int i = 0; i < CHS; ++i){
    int ro = i*56;
    float dtr = dbias;
    #pragma unroll
    for (int j = 0; j < DTR; ++j) dtr += w[j] * sRow[ro + j];
    float dtv = fsoftplus(dtr);
    sumdt += dtv;
    float du = dtv * sU[i*256 + t];
    #pragma unroll
    for (int s = 0; s < DSt; ++s)
      h[s] = exp2f(dtv * a2[s]) * h[s] + du * sRow[ro + 24 + s];
  }
  size_t sb = ((size_t)blk*256 + t)*16;
  #pragma unroll
  for (int s = 0; s < DSt; ++s) SB_S[sb + s] = h[s];
  SB_dt[(size_t)blk*256 + t] = sumdt;
}

__global__ __launch_bounds__(256) void scanB_kernel(float* __restrict__ ydst_base, int ys,
                                                    const float* __restrict__ usrc, int uld,
                                                    const float* __restrict__ xdb,
                                                    const float* __restrict__ dpw,
                                                    const float* __restrict__ dpb,
                                                    const float* __restrict__ A_log,
                                                    const float* __restrict__ Dp,
                                                    const float* __restrict__ SB_S,
                                                    const float* __restrict__ SB_dt){
  __shared__ float sRow[CHS*56];
  __shared__ float sU[CHS*256];
  int blk = blockIdx.x;
  int c = blk % NCH; int bd = blk / NCH; int dch = bd % 3; int b = bd / 3;
  int t = threadIdx.x; int d = dch*256 + t;
  int l0 = c*CHS;
  for (int i = t; i < CHS*56; i += 256) sRow[i] = xdb[((size_t)(b*Ln + l0))*56 + i];
  const float* up = usrc + ((size_t)(b*Ln + l0))*uld + dch*256;
  #pragma unroll
  for (int i = 0; i < CHS; ++i) sU[i*256 + t] = up[(size_t)i*uld + t];
  float w[DTR];
  const float* wp = dpw + (size_t)d*DTR;
  #pragma unroll
  for (int j = 0; j < DTR; ++j) w[j] = wp[j];
  float a2[DSt], h[DSt];
  const float* ap = A_log + (size_t)d*DSt;
  #pragma unroll
  for (int s = 0; s < DSt; ++s){ a2[s] = -__expf(ap[s]) * LOG2E; h[s] = 0.f; }
  for (int cc = 0; cc < c; ++cc){
    size_t base = (((size_t)bd*NCH + cc)*256 + t)*16;
    float sd = SB_dt[((size_t)bd*NCH + cc)*256 + t];
    #pragma unroll
    for (int s = 0; s < DSt; ++s)
      h[s] = exp2f(sd * a2[s]) * h[s] + SB_S[base + s];
  }
  float dbias = dpb[d];
  float Dd = Dp[d];
  float* ydst = ydst_base + ((size_t)(b*Ln + l0))*ys + dch*256;
  __syncthreads();
  for (int i = 0; i < CHS; ++i){
    int ro = i*56;
    float dtr = dbias;
    #pragma unroll
    for (int j = 0; j < DTR; ++j) dtr += w[j] * sRow[ro + j];
    float dtv = fsoftplus(dtr);
    float u = sU[i*256 + t];
    float du = dtv * u;
    float yv = 0.f;
    #pragma unroll
    for (int s = 0; s < DSt; ++s){
      h[s] = exp2f(dtv * a2[s]) * h[s] + du * sRow[ro + 24 + s];
      yv += h[s] * sRow[ro + 40 + s];
    }
    ydst[(size_t)i*ys + t] = yv + u*Dd;
  }
}

// -------------------------------------------------- final two LayerNorms
__global__ __launch_bounds__(256) void final_ln_kernel(const float* __restrict__ h,
                                                       const float* __restrict__ res,
                                                       const float* w1, const float* b1,
                                                       const float* w2, const float* b2,
                                                       float* __restrict__ x){
  int wv = threadIdx.x >> 6, ln = threadIdx.x & 63;
  int tokid = blockIdx.x*4 + wv;
  const float* hr = h + (size_t)tokid*DM;
  const float* rr = res + (size_t)tokid*DM;
  float* xr = x + (size_t)tokid*DM;
  float v[6]; float s = 0.f;
  #pragma unroll
  for (int i = 0; i < 6; ++i){ int c = ln + 64*i; v[i] = hr[c] + rr[c]; s += v[i]; }
  #pragma unroll
  for (int o = 32; o > 0; o >>= 1) s += __shfl_xor(s, o);
  float mu = s * (1.f/DM); float q = 0.f;
  #pragma unroll
  for (int i = 0; i < 6; ++i){ float dd = v[i]-mu; q += dd*dd; }
  #pragma unroll
  for (int o = 32; o > 0; o >>= 1) q += __shfl_xor(q, o);
  float rstd = rsqrtf(q * (1.f/DM) + EPSf);
  float u[6]; float s2 = 0.f;
  #pragma unroll
  for (int i = 0; i < 6; ++i){ int c = ln + 64*i; u[i] = (v[i]-mu)*rstd*w1[c] + b1[c]; s2 += u[i]; }
  #pragma unroll
  for (int o = 32; o > 0; o >>= 1) s2 += __shfl_xor(s2, o);
  float mu2 = s2 * (1.f/DM); float q2 = 0.f;
  #pragma unroll
  for (int i = 0; i < 6; ++i){ float dd = u[i]-mu2; q2 += dd*dd; }
  #pragma unroll
  for (int o = 32; o > 0; o >>= 1) q2 += __shfl_xor(q2, o);
  float rstd2 = rsqrtf(q2 * (1.f/DM) + EPSf);
  #pragma unroll
  for (int i = 0; i < 6; ++i){ int c = ln + 64*i; xr[c] = (u[i]-mu2)*rstd2*w2[c] + b2[c]; }
}

// -------------------------------------------------- mean over L + MLP head
__global__ __launch_bounds__(384) void head_kernel(const float* __restrict__ x,
    const float* w1, const float* b1, const float* g1, const float* bb1,
    const float* w2, const float* b2, const float* g2, const float* bb2,
    const float* w3, const float* b3, float* __restrict__ out){
  int b = blockIdx.x; int t = threadIdx.x;
  __shared__ float feat[DM]; __shared__ float h1[256]; __shared__ float h2[256];
  float s = 0.f;
  for (int l = 0; l < Ln; ++l) s += x[((size_t)(b*Ln + l))*DM + t];
  feat[t] = s * (1.f/Ln);
  __syncthreads();
  if (t < 256){
    float a = b1[t];
    for (int j = 0; j < DM; ++j) a += w1[(size_t)t*DM + j] * feat[j];
    a = a * (g1[t] * BNS) + bb1[t];
    h1[t] = fmaxf(a, 0.f);
  }
  __syncthreads();
  if (t < 256){
    float a = b2[t];
    for (int j = 0; j < 256; ++j) a += w2[(size_t)t*256 + j] * h1[j];
    a = a * (g2[t] * BNS) + bb2[t];
    h2[t] = fmaxf(a, 0.f);
  }
  __syncthreads();
  if (t < CLSn){
    float a = b3[t];
    for (int j = 0; j < 256; ++j) a += w3[(size_t)t*256 + j] * h2[j];
    out[b*CLSn + t] = a;
  }
}

extern "C" void kernel_launch(void* const* d_in, const int* in_sizes, int n_in,
                              void* d_out, int out_size, void* d_ws, size_t ws_size,
                              hipStream_t stream) {
  if (n_in < 42) return;
  if (out_size < Bn*CLSn) return;
  constexpr size_t WS_FLOATS = 3919936;
  if (ws_size < WS_FLOATS * sizeof(float)) return;
  constexpr size_t MIDF = 5812224;
  constexpr size_t BIGF = 18874368;
  const bool mid = ws_size >= (WS_FLOATS + MIDF) * sizeof(float);
  const bool big = ws_size >= (WS_FLOATS + MIDF + BIGF) * sizeof(float);

  const float* pts       = (const float*)d_in[0];
  const float* enc_w1    = (const float*)d_in[1];  const float* enc_b1    = (const float*)d_in[2];
  const float* enc_bn1_g = (const float*)d_in[3];  const float* enc_bn1_b = (const float*)d_in[4];
  const float* enc_w2    = (const float*)d_in[5];  const float* enc_b2    = (const float*)d_in[6];
  const float* enc_w3    = (const float*)d_in[7];  const float* enc_b3    = (const float*)d_in[8];
  const float* enc_bn2_g = (const float*)d_in[9];  const float* enc_bn2_b = (const float*)d_in[10];
  const float* enc_w4    = (const float*)d_in[11]; const float* enc_b4    = (const float*)d_in[12];
  const float* pos_w1    = (const float*)d_in[13]; const float* pos_b1    = (const float*)d_in[14];
  const float* pos_w2    = (const float*)d_in[15]; const float* pos_b2    = (const float*)d_in[16];
  const float* ln_w      = (const float*)d_in[17]; const float* ln_b      = (const float*)d_in[18];
  const float* in_proj_w = (const float*)d_in[19];
  const float* conv_w    = (const float*)d_in[20]; const float* conv_b    = (const float*)d_in[21];
  const float* x_proj_w  = (const float*)d_in[22];
  const float* dt_proj_w = (const float*)d_in[23]; const float* dt_proj_b = (const float*)d_in[24];
  const float* A_log     = (const float*)d_in[25]; const float* D_param   = (const float*)d_in[26];
  const float* out_proj_w= (const float*)d_in[27];
  const float* normf_w   = (const float*)d_in[28]; const float* normf_b   = (const float*)d_in[29];
  const float* norm_w    = (const float*)d_in[30]; const float* norm_b    = (const float*)d_in[31];
  const float* head_w1   = (const float*)d_in[32]; const float* head_b1   = (const float*)d_in[33];
  const float* head_bn1_g= (const float*)d_in[34]; const float* head_bn1_b= (const float*)d_in[35];
  const float* head_w2   = (const float*)d_in[36]; const float* head_b2   = (const float*)d_in[37];
  const float* head_bn2_g= (const float*)d_in[38]; const float* head_bn2_b= (const float*)d_in[39];
  const float* head_w3   = (const float*)d_in[40]; const float* head_b3   = (const float*)d_in[41];

  float* ws = (float*)d_ws;
  float* hb   = ws;
  float* resb = ws + 589824;
  float* U    = ws + 1179648;
  float* center = U;
  float* nb     = U + 1536;
  float* tok    = U + 50688;
  int*   order  = (int*)(U + 247296);
  float* eb0    = U + 262144;
  float* eb1    = U + 1310720;
  float* xz   = U;
  float* xdb  = U + 2359296;
  bf16*  xb   = (bf16*)(U + 2445312);
  float* SBdt_s = U + 2445312;
  float* BND  = U + 2482176;
  float* SBS_s  = hb;
  float* xf   = U;
  float* WB = ws + WS_FLOATS;
  bf16* wb_ip = (bf16*)WB;
  bf16* wb_op = (bf16*)(WB + 3538944);
  bf16* wb_xp = (bf16*)(WB + 5308416);
  bf16* wb_e2 = (bf16*)(WB + 5566464);
  bf16* wb_e3 = (bf16*)(WB + 5582848);
  bf16* wb_e4 = (bf16*)(WB + 5713920);
  float* F3in = WB + MIDF;
  float* F3   = WB + MIDF + 8388608;
  float* F1   = WB + MIDF + 16777216;
  float* F4   = F3in;
  float* ucv  = F3in;
  float* SBS_b  = F3;
  float* SBdt_b = F1;

  if (mid)
    cvt_all<<<11352, 256, 0, stream>>>(in_proj_w, out_proj_w, x_proj_w,
                                       enc_w2, enc_w3, enc_w4, (bf16*)WB);

  fps_kernel<<<Bn, 64, 0, stream>>>(pts, center);
  knn_kernel<<<Bn*Gn, 256, 0, stream>>>(pts, center, nb);

  if (big){
    gemm_mfma<float,float,1,0><<<dim3(256,2), 256, 0, stream>>>(nb, 3, enc_w1, enc_b1,
        enc_bn1_g, enc_bn1_b, F1, 128, 16384, 128, 3);
    gemm_mfma64<float,bf16,0,0><<<dim3(256,4), 256, 0, stream>>>(F1, 128, wb_e2, enc_b2,
        nullptr, nullptr, F3in + 256, 512, 16384, 256, 128);
    maxk_fg<<<512, 256, 0, stream>>>(F3in);
    gemm_mfma64<float,bf16,1,0><<<dim3(256,8), 256, 0, stream>>>(F3in, 512, wb_e3, enc_b3,
        enc_bn2_g, enc_bn2_b, F3, 512, 16384, 512, 512);
    gemm_mfma64<float,bf16,0,0><<<dim3(256,6), 256, 0, stream>>>(F3, 512, wb_e4, enc_b4,
        nullptr, nullptr, F4, 384, 16384, 384, 512);
    maxk_tok<<<512, 384, 0, stream>>>(F4, tok);
  } else {
    for (int ch = 0; ch < 8; ++ch){
      const float* nb_c = nb + (size_t)ch*2048*3;
      float* tok_c = tok + (size_t)ch*64*DM;
      gemm_mfma<float,float,1,0><<<dim3(32,2), 256, 0, stream>>>(nb_c, 3, enc_w1, enc_b1,
          enc_bn1_g, enc_bn1_b, eb1, 128, 2048, 128, 3);
      if (mid){
        gemm_mfma64<float,bf16,0,0><<<dim3(32,4), 256, 0, stream>>>(eb1, 128, wb_e2, enc_b2,
            nullptr, nullptr, eb0 + 256, 512, 2048, 256, 128);
        maxk_fg<<<64, 256, 0, stream>>>(eb0);
        gemm_mfma64<float,bf16,1,0><<<dim3(32,8), 256, 0, stream>>>(eb0, 512, wb_e3, enc_b3,
            enc_bn2_g, enc_bn2_b, eb1, 512, 2048, 512, 512);
        gemm_mfma64<float,bf16,0,0><<<dim3(32,6), 256, 0, stream>>>(eb1, 512, wb_e4, enc_b4,
            nullptr, nullptr, eb0, 384, 2048, 384, 512);
      } else {
        gemm_mfma64<float,float,0,0><<<dim3(32,4), 256, 0, stream>>>(eb1, 128, enc_w2, enc_b2,
            nullptr, nullptr, eb0 + 256, 512, 2048, 256, 128);
        maxk_fg<<<64, 256, 0, stream>>>(eb0);
        gemm_mfma64<float,float,1,0><<<dim3(32,8), 256, 0, stream>>>(eb0, 512, enc_w3, enc_b3,
            enc_bn2_g, enc_bn2_b, eb1, 512, 2048, 512, 512);
        gemm_mfma64<float,float,0,0><<<dim3(32,6), 256, 0, stream>>>(eb1, 512, enc_w4, enc_b4,
            nullptr, nullptr, eb0, 384, 2048, 384, 512);
      }
      maxk_tok<<<64, 384, 0, stream>>>(eb0, tok_c);
    }
  }

  pos_kernel<<<Bn*Gn, 128, 0, stream>>>(center, pos_w1, pos_b1, pos_w2, pos_b2, tok);
  sort_kernel<<<Bn*3, 128, 0, stream>>>(center, order);
  build_h<<<(Bn*Ln*DM + 255)/256, 256, 0, stream>>>(tok, order, hb, resb);

  for (int l = 0; l < DEPTH; ++l){
    const float* lnw  = ln_w      + (size_t)l*DM;
    const float* lnb  = ln_b      + (size_t)l*DM;
    const float* ipw  = in_proj_w + (size_t)l*1536*DM;
    const float* cw   = conv_w    + (size_t)l*DI*4;
    const float* cb   = conv_b    + (size_t)l*DI;
    const float* xpw  = x_proj_w  + (size_t)l*56*DI;
    const float* dpw  = dt_proj_w + (size_t)l*DI*DTR;
    const float* dpb  = dt_proj_b + (size_t)l*DI;
    const float* Alg  = A_log     + (size_t)l*DI*DSt;
    const float* Dpar = D_param   + (size_t)l*DI;
    const float* opw  = out_proj_w+ (size_t)l*DM*DI;

    ln_res_kernel<<<Bn*Ln/4, 256, 0, stream>>>(hb, resb, xb, lnw, lnb);
    if (mid){
      gemm_mfma64<bf16,bf16,0,0><<<dim3(24,24), 256, 0, stream>>>(xb, DM,
          wb_ip + (size_t)l*1536*DM, nullptr, nullptr, nullptr, xz, 1536, Bn*Ln, 1536, DM);
    } else {
      gemm_mfma64<bf16,float,0,0><<<dim3(24,24), 256, 0, stream>>>(xb, DM, ipw,
          nullptr, nullptr, nullptr, xz, 1536, Bn*Ln, 1536, DM);
    }
    if (big){
      conv_fused<<<Bn*3*NLC, 256, 0, stream>>>(xz, ucv, cw, cb);
      if (mid)
        gemm_mfma64<float,bf16,0,0><<<dim3(24,1), 256, 0, stream>>>(ucv, DI,
            wb_xp + (size_t)l*56*DI, nullptr, nullptr, nullptr, xdb, 56, Bn*Ln, 56, DI);
      else
        gemm_mfma64<float,float,0,0><<<dim3(24,1), 256, 0, stream>>>(ucv, DI, xpw,
            nullptr, nullptr, nullptr, xdb, 56, Bn*Ln, 56, DI);
      scanA_kernel<<<Bn*3*NCH, 256, 0, stream>>>(ucv, DI, xdb, dpw, dpb, Alg, SBS_b, SBdt_b);
      scanB_kernel<<<Bn*3*NCH, 256, 0, stream>>>(xz, 1536, ucv, DI,
          xdb, dpw, dpb, Alg, Dpar, SBS_b, SBdt_b);
    } else {
      conv_save<<<Bn*3*NLC, 256, 0, stream>>>(xz, BND);
      conv_apply<<<Bn*3*NLC, 256, 0, stream>>>(xz, BND, cw, cb);
      if (mid)
        gemm_mfma64<float,bf16,0,0><<<dim3(24,1), 256, 0, stream>>>(xz, 1536,
            wb_xp + (size_t)l*56*DI, nullptr, nullptr, nullptr, xdb, 56, Bn*Ln, 56, DI);
      else
        gemm_mfma64<float,float,0,0><<<dim3(24,1), 256, 0, stream>>>(xz, 1536, xpw,
            nullptr, nullptr, nullptr, xdb, 56, Bn*Ln, 56, DI);
      scanA_kernel<<<Bn*3*NCH, 256, 0, stream>>>(xz, 1536, xdb, dpw, dpb, Alg, SBS_s, SBdt_s);
      scanB_kernel<<<Bn*3*NCH, 256, 0, stream>>>(xz, 1536, xz, 1536,
          xdb, dpw, dpb, Alg, Dpar, SBS_s, SBdt_s);
    }
    if (mid){
      gemm_mfma64<float,bf16,1-1,1><<<dim3(24,6), 256, 0, stream>>>(xz, 1536,
          wb_op + (size_t)l*DM*DI, nullptr, xz, nullptr, hb, DM, Bn*Ln, DM, DI);
    } else {
      gemm_mfma64<float,float,0,1><<<dim3(24,6), 256, 0, stream>>>(xz, 1536, opw,
          nullptr, xz, nullptr, hb, DM, Bn*Ln, DM, DI);
    }
  }

  final_ln_kernel<<<Bn*Ln/4, 256, 0, stream>>>(hb, resb, normf_w, normf_b, norm_w, norm_b, xf);
  head_kernel<<<Bn, 384, 0, stream>>>(xf, head_w1, head_b1, head_bn1_g, head_bn1_b,
                                      head_w2, head_b2, head_bn2_g, head_bn2_b,
                                      head_w3, head_b3, (float*)d_out);
}